// Round 9
// baseline (160.040 us; speedup 1.0000x reference)
//
#include <hip/hip_runtime.h>
#include <hip/hip_bf16.h>
#include <math.h>

#define Bb   16
#define Ll   2048
#define Dd   1024
#define OSo  64
#define NCc  256
#define LABh 1024
#define BN_EPS 1e-5f

typedef short s8v  __attribute__((ext_vector_type(8)));   // 8 bf16 = 4 VGPR
typedef short s4v  __attribute__((ext_vector_type(4)));
typedef float f32x4 __attribute__((ext_vector_type(4)));

__device__ __forceinline__ short f2b(float f) {
    __hip_bfloat16 h = __float2bfloat16(f);
    short s;
    __builtin_memcpy(&s, &h, 2);
    return s;
}
__device__ __forceinline__ float b2f(short s) {
    union { unsigned u; float f; } v; v.u = ((unsigned)(unsigned short)s) << 16;
    return v.f;
}
// Barrier without vmcnt(0) drain (k3 only).
__device__ __forceinline__ void fastbar() {
    asm volatile("s_waitcnt lgkmcnt(0)\n\ts_barrier" ::: "memory");
}
// swizzled short-index into a [rows][64] bf16 LDS tile (row stride 128B).
__device__ __forceinline__ int swi(int row, int kElem) {
    return (row * 128 + ((kElem * 2) ^ ((row & 7) << 4))) >> 1;
}
__device__ __forceinline__ f32x4 MF(s8v a, s8v b, f32x4 c) {
    return __builtin_amdgcn_mfma_f32_16x16x32_bf16(a, b, c, 0, 0, 0);
}

// ---------------------------------------------------------------------------
// k0: transpose+convert weights.
// ---------------------------------------------------------------------------
__global__ __launch_bounds__(256) void k0(const float* __restrict__ h_w,
                                          const float* __restrict__ a_w,
                                          short* __restrict__ h_wT,
                                          short* __restrict__ a_wT) {
    __shared__ float t[64][68];
    const int tid = threadIdx.x, id = blockIdx.x;
    const float* src; short* dst; int srw, d0, y0;
    if (id < 256) { src = h_w; dst = h_wT; srw = LABh; d0 = (id & 15) * 64; y0 = (id >> 4) * 64; }
    else          { src = a_w; dst = a_wT; srw = OSo;  d0 = (id - 256) * 64; y0 = 0; }
    const int r = tid >> 2, cofs = (tid & 3) * 16;
    #pragma unroll
    for (int w = 0; w < 4; ++w) {
        float4 v = *(const float4*)&src[(size_t)(d0 + r) * srw + y0 + cofs + w * 4];
        t[r][cofs + w * 4 + 0] = v.x;
        t[r][cofs + w * 4 + 1] = v.y;
        t[r][cofs + w * 4 + 2] = v.z;
        t[r][cofs + w * 4 + 3] = v.w;
    }
    __syncthreads();
    s8v o0, o1;
    #pragma unroll
    for (int e = 0; e < 8; ++e) { o0[e] = f2b(t[cofs + e][r]); o1[e] = f2b(t[cofs + 8 + e][r]); }
    *(s8v*)&dst[(size_t)(y0 + r) * Dd + d0 + cofs]     = o0;
    *(s8v*)&dst[(size_t)(y0 + r) * Dd + d0 + cofs + 8] = o1;
}

// ---------------------------------------------------------------------------
// k1: St[b][o][l] = X@a_w + a_b.  tile 64(l)x64(o), K=1024.
// LDS-FREE main loop: per-lane direct fragment loads from global
// (row = base+(lane&15), k = k0+(lane>>4)*8 — fully line-coalesced).
// No barriers in the K-loop; 4 waves run free.
// ---------------------------------------------------------------------------
__global__ __launch_bounds__(256) void k1(const float* __restrict__ X,
                                          const short* __restrict__ a_wT,
                                          const float* __restrict__ a_b,
                                          float* __restrict__ St) {
    __shared__ float ts[64][65];
    const int tid = threadIdx.x, lane = tid & 63, wave = tid >> 6;
    const int wm = wave >> 1, wn = wave & 1;
    const int b = blockIdx.y, l0 = blockIdx.x * 64;
    const int rA = wm * 32 + (lane & 15);
    const int rB = wn * 32 + (lane & 15);
    const int klane = (lane >> 4) * 8;
    const float* Xb = X + ((size_t)b * Ll + l0) * Dd;
    f32x4 acc[2][2] = {};
    #pragma unroll 4
    for (int k0 = 0; k0 < Dd; k0 += 32) {
        s8v a[2], bb[2];
        #pragma unroll
        for (int i = 0; i < 2; ++i) {
            const float* p = &Xb[(size_t)(rA + i * 16) * Dd + k0 + klane];
            float4 v0 = *(const float4*)p;
            float4 v1 = *(const float4*)(p + 4);
            s8v s;
            s[0]=f2b(v0.x); s[1]=f2b(v0.y); s[2]=f2b(v0.z); s[3]=f2b(v0.w);
            s[4]=f2b(v1.x); s[5]=f2b(v1.y); s[6]=f2b(v1.z); s[7]=f2b(v1.w);
            a[i] = s;
        }
        #pragma unroll
        for (int j = 0; j < 2; ++j)
            bb[j] = *(const s8v*)&a_wT[(size_t)(rB + j * 16) * Dd + k0 + klane];
        #pragma unroll
        for (int i = 0; i < 2; ++i)
            #pragma unroll
            for (int j = 0; j < 2; ++j)
                acc[i][j] = MF(a[i], bb[j], acc[i][j]);
    }
    // epilogue: ts[l][o] then write St[o][l] rows
    #pragma unroll
    for (int i = 0; i < 2; ++i)
        #pragma unroll
        for (int j = 0; j < 2; ++j)
            #pragma unroll
            for (int rr = 0; rr < 4; ++rr)
                ts[wm * 32 + i * 16 + (lane >> 4) * 4 + rr][wn * 32 + j * 16 + (lane & 15)] = acc[i][j][rr];
    __syncthreads();
    const int o = tid >> 2, lofs = (tid & 3) * 16;
    const float bias = a_b[o];
    float* Sp = St + ((size_t)b * OSo + o) * Ll + l0 + lofs;
    #pragma unroll
    for (int w = 0; w < 4; ++w) {
        float4 v;
        v.x = ts[lofs + w * 4 + 0][o] + bias;
        v.y = ts[lofs + w * 4 + 1][o] + bias;
        v.z = ts[lofs + w * 4 + 2][o] + bias;
        v.w = ts[lofs + w * 4 + 3][o] + bias;
        *(float4*)&Sp[w * 4] = v;
    }
}

// ---------------------------------------------------------------------------
// k2: softmax over L per (b,o) row; St f32 in -> alpha bf16 out
// ---------------------------------------------------------------------------
__global__ __launch_bounds__(256) void k2(const float* __restrict__ St, short* __restrict__ aBf) {
    __shared__ float row[Ll];
    __shared__ float red[8];
    const float* p = St + (size_t)blockIdx.x * Ll;
    short* ab = aBf + (size_t)blockIdx.x * Ll;
    const int tid = threadIdx.x;
    const int wave = tid >> 6, lane = tid & 63;
    float m = -1e30f;
    for (int i = tid; i < Ll; i += 256) { float v = p[i]; row[i] = v; m = fmaxf(m, v); }
    #pragma unroll
    for (int off = 32; off; off >>= 1) m = fmaxf(m, __shfl_down(m, off));
    if (lane == 0) red[wave] = m;
    __syncthreads();
    if (tid == 0) red[4] = fmaxf(fmaxf(red[0], red[1]), fmaxf(red[2], red[3]));
    __syncthreads();
    const float M = red[4];
    float s = 0.f;
    for (int i = tid; i < Ll; i += 256) { float e = __expf(row[i] - M); row[i] = e; s += e; }
    __syncthreads();
    #pragma unroll
    for (int off = 32; off; off >>= 1) s += __shfl_down(s, off);
    if (lane == 0) red[wave] = s;
    __syncthreads();
    if (tid == 0) red[4] = 1.f / (red[0] + red[1] + red[2] + red[3]);
    __syncthreads();
    const float inv = red[4];
    for (int i = tid; i < Ll; i += 256) ab[i] = f2b(row[i] * inv);
}

// ---------------------------------------------------------------------------
// k3: Xp_part[z] = alpha_half @ X_half.  tile 64(o)x64(d), split-K=2,
// dbuf+prefetch (LDS needed: X must be transposed).  Unchanged from best.
// ---------------------------------------------------------------------------
struct R3 { s8v al[2]; float4 xv[4]; };

__global__ __launch_bounds__(256) void k3(const float* __restrict__ X,
                                          const short* __restrict__ aBf,
                                          float* __restrict__ XpP) {
    __shared__ __align__(16) char smem[32768];
    float (*ts)[68] = (float(*)[68])smem;                   // epilogue alias
    const int tid = threadIdx.x;
    const int lane = tid & 63, wave = tid >> 6;
    const int wm = wave >> 1, wn = wave & 1;
    const int id = blockIdx.x;
    const int slot = id >> 3;
    const int b = (id & 7) * 2 + (slot >> 5);
    const int inner = slot & 31;
    const int dt = inner & 15, z = inner >> 4;
    const int d0 = dt * 64;
    const float* Xb = X + (size_t)b * Ll * Dd;
    const short* ab = aBf + (size_t)b * OSo * Ll;
    float* outP = XpP + (size_t)z * ((size_t)Bb * OSo * Dd);
    f32x4 acc[2][2] = {};
    const int arow = tid >> 2, akofs = (tid & 3) * 16;
    const int lq = tid & 15, dq = tid >> 4;
    const int lbase = z * 1024;
    R3 cur, nxt;
    #pragma unroll
    for (int w = 0; w < 2; ++w)
        cur.al[w] = *(const s8v*)&ab[(size_t)arow * Ll + lbase + akofs + w * 8];
    #pragma unroll
    for (int i = 0; i < 4; ++i)
        cur.xv[i] = *(const float4*)&Xb[(size_t)(lbase + lq * 4 + i) * Dd + d0 + dq * 4];
    #pragma unroll
    for (int t = 0; t < 16; ++t) {
        short* Aal = (short*)(smem + (t & 1) * 8192);
        short* Xs  = (short*)(smem + 16384 + (t & 1) * 8192);
        #pragma unroll
        for (int w = 0; w < 2; ++w)
            *(s8v*)&Aal[swi(arow, akofs + w * 8)] = cur.al[w];
        {
            const float* f = (const float*)cur.xv;          // f[i*4+j] = X[l=lq*4+i][d=dq*4+j]
            #pragma unroll
            for (int j = 0; j < 4; ++j) {
                const int rowd = dq * 4 + j;
                s4v sj;
                sj[0] = f2b(f[0 * 4 + j]);
                sj[1] = f2b(f[1 * 4 + j]);
                sj[2] = f2b(f[2 * 4 + j]);
                sj[3] = f2b(f[3 * 4 + j]);
                *(s4v*)&Xs[swi(rowd, lq * 4)] = sj;
            }
        }
        fastbar();
        if (t < 15) {
            const int l0 = lbase + (t + 1) * 64;
            #pragma unroll
            for (int w = 0; w < 2; ++w)
                nxt.al[w] = *(const s8v*)&ab[(size_t)arow * Ll + l0 + akofs + w * 8];
            #pragma unroll
            for (int i = 0; i < 4; ++i)
                nxt.xv[i] = *(const float4*)&Xb[(size_t)(l0 + lq * 4 + i) * Dd + d0 + dq * 4];
        }
        #pragma unroll
        for (int kk = 0; kk < 2; ++kk) {
            const int kb = kk * 32 + (lane >> 4) * 8;
            s8v a[2], bb[2];
            #pragma unroll
            for (int i = 0; i < 2; ++i)
                a[i] = *(const s8v*)&Aal[swi(wm * 32 + i * 16 + (lane & 15), kb)];
            #pragma unroll
            for (int j = 0; j < 2; ++j)
                bb[j] = *(const s8v*)&Xs[swi(wn * 32 + j * 16 + (lane & 15), kb)];
            #pragma unroll
            for (int i = 0; i < 2; ++i)
                #pragma unroll
                for (int j = 0; j < 2; ++j)
                    acc[i][j] = MF(a[i], bb[j], acc[i][j]);
        }
        if (t < 15) cur = nxt;
    }
    __syncthreads();
    #pragma unroll
    for (int i = 0; i < 2; ++i)
        #pragma unroll
        for (int j = 0; j < 2; ++j)
            #pragma unroll
            for (int rr = 0; rr < 4; ++rr)
                ts[wm * 32 + i * 16 + (lane >> 4) * 4 + rr][wn * 32 + j * 16 + (lane & 15)] = acc[i][j][rr];
    __syncthreads();
    const int o = tid >> 2, dofs = (tid & 3) * 16;
    float* op = outP + ((size_t)b * OSo + o) * Dd + d0 + dofs;
    #pragma unroll
    for (int w = 0; w < 4; ++w)
        *(float4*)&op[w * 4] = *(float4*)&ts[o][dofs + w * 4];
}

// ---------------------------------------------------------------------------
// k4: Xh = bf16(relu(BN((XpP0+XpP1)@h_w + h_b)))  tile 64(m)x64(h), K=1024.
// LDS-FREE: direct fragment loads (Xp partials summed in regs; h_wT bf16).
// ---------------------------------------------------------------------------
__global__ __launch_bounds__(256) void k4(const float* __restrict__ XpP,
                                          const short* __restrict__ h_wT,
                                          const float* __restrict__ h_b,
                                          const float* __restrict__ gamma,
                                          const float* __restrict__ beta,
                                          const float* __restrict__ mean,
                                          const float* __restrict__ var,
                                          short* __restrict__ Xh) {
    __shared__ short tsb[64 * 64];
    const int tid = threadIdx.x, lane = tid & 63, wave = tid >> 6;
    const int wm = wave >> 1, wn = wave & 1;
    const int h0 = blockIdx.x * 64, m0 = blockIdx.y * 64;
    const int rA = wm * 32 + (lane & 15);
    const int rB = wn * 32 + (lane & 15);
    const int klane = (lane >> 4) * 8;
    const size_t ZS = (size_t)Bb * OSo * Dd;
    f32x4 acc[2][2] = {};
    #pragma unroll 4
    for (int k0 = 0; k0 < Dd; k0 += 32) {
        s8v a[2], bb[2];
        #pragma unroll
        for (int i = 0; i < 2; ++i) {
            const float* p0 = XpP + (size_t)(m0 + rA + i * 16) * Dd + k0 + klane;
            float4 u0 = *(const float4*)p0;
            float4 u1 = *(const float4*)(p0 + 4);
            float4 w0 = *(const float4*)(p0 + ZS);
            float4 w1 = *(const float4*)(p0 + ZS + 4);
            s8v s;
            s[0]=f2b(u0.x+w0.x); s[1]=f2b(u0.y+w0.y); s[2]=f2b(u0.z+w0.z); s[3]=f2b(u0.w+w0.w);
            s[4]=f2b(u1.x+w1.x); s[5]=f2b(u1.y+w1.y); s[6]=f2b(u1.z+w1.z); s[7]=f2b(u1.w+w1.w);
            a[i] = s;
        }
        #pragma unroll
        for (int j = 0; j < 2; ++j)
            bb[j] = *(const s8v*)&h_wT[(size_t)(h0 + rB + j * 16) * Dd + k0 + klane];
        #pragma unroll
        for (int i = 0; i < 2; ++i)
            #pragma unroll
            for (int j = 0; j < 2; ++j)
                acc[i][j] = MF(a[i], bb[j], acc[i][j]);
    }
    #pragma unroll
    for (int j = 0; j < 2; ++j) {
        const int h = h0 + wn * 32 + j * 16 + (lane & 15);
        const float sc = gamma[h] * rsqrtf(var[h] + BN_EPS);
        const float of = (h_b[h] - mean[h]) * sc + beta[h];
        #pragma unroll
        for (int i = 0; i < 2; ++i)
            #pragma unroll
            for (int rr = 0; rr < 4; ++rr) {
                const int ml = wm * 32 + i * 16 + (lane >> 4) * 4 + rr;
                tsb[ml * 64 + wn * 32 + j * 16 + (lane & 15)] = f2b(fmaxf(0.f, acc[i][j][rr] * sc + of));
            }
    }
    __syncthreads();
    const int r = tid >> 2, kofs = (tid & 3) * 16;
    #pragma unroll
    for (int w = 0; w < 2; ++w)
        *(s8v*)&Xh[(size_t)(m0 + r) * LABh + h0 + kofs + w * 8] = *(const s8v*)&tsb[r * 64 + kofs + w * 8];
}

// ---------------------------------------------------------------------------
// k5: scP[z][b][c][o] partial over K range z.  tile 64(c)x64(o), split-K=4.
// LDS-FREE: direct fragment loads (labD gather rows f32; Xh bf16).
// grid (16, 16): x = ct(0..3) + 4*z(0..3).
// ---------------------------------------------------------------------------
__global__ __launch_bounds__(256) void k5(const int* __restrict__ cand,
                                          const float* __restrict__ labD,
                                          const short* __restrict__ Xh,
                                          float* __restrict__ scP) {
    __shared__ float ts[64][68];
    __shared__ int cidx[64];
    const int tid = threadIdx.x, lane = tid & 63, wave = tid >> 6;
    const int wm = wave >> 1, wn = wave & 1;
    const int b = blockIdx.y;
    const int ct = blockIdx.x & 3, z = blockIdx.x >> 2;
    const int c0 = ct * 64;
    const int kbase = z * 256;
    if (tid < 64) cidx[tid] = cand[b * NCc + c0 + tid];
    __syncthreads();
    const int rA = wm * 32 + (lane & 15);
    const int rB = wn * 32 + (lane & 15);
    const int klane = (lane >> 4) * 8;
    const int ciA0 = cidx[rA], ciA1 = cidx[rA + 16];
    const float* lr0 = labD + (size_t)ciA0 * LABh + kbase + klane;
    const float* lr1 = labD + (size_t)ciA1 * LABh + kbase + klane;
    const short* xb  = Xh + (size_t)b * OSo * LABh + kbase + klane;
    f32x4 acc[2][2] = {};
    #pragma unroll 2
    for (int k0 = 0; k0 < 256; k0 += 32) {
        s8v a[2], bb[2];
        #pragma unroll
        for (int i = 0; i < 2; ++i) {
            const float* p = (i == 0 ? lr0 : lr1) + k0;
            float4 v0 = *(const float4*)p;
            float4 v1 = *(const float4*)(p + 4);
            s8v s;
            s[0]=f2b(v0.x); s[1]=f2b(v0.y); s[2]=f2b(v0.z); s[3]=f2b(v0.w);
            s[4]=f2b(v1.x); s[5]=f2b(v1.y); s[6]=f2b(v1.z); s[7]=f2b(v1.w);
            a[i] = s;
        }
        #pragma unroll
        for (int j = 0; j < 2; ++j)
            bb[j] = *(const s8v*)&xb[(size_t)(rB + j * 16) * LABh + k0];
        #pragma unroll
        for (int i = 0; i < 2; ++i)
            #pragma unroll
            for (int j = 0; j < 2; ++j)
                acc[i][j] = MF(a[i], bb[j], acc[i][j]);
    }
    #pragma unroll
    for (int i = 0; i < 2; ++i)
        #pragma unroll
        for (int j = 0; j < 2; ++j)
            #pragma unroll
            for (int rr = 0; rr < 4; ++rr)
                ts[wm * 32 + i * 16 + (lane >> 4) * 4 + rr][wn * 32 + j * 16 + (lane & 15)] = acc[i][j][rr];
    __syncthreads();
    const int r = tid >> 2, oofs = (tid & 3) * 16;
    float* sp = scP + (size_t)z * ((size_t)Bb * NCc * OSo)
                    + ((size_t)b * NCc + c0 + r) * OSo + oofs;
    #pragma unroll
    for (int w = 0; w < 4; ++w)
        *(float4*)&sp[w * 4] = *(float4*)&ts[r][oofs + w * 4];
}

// ---------------------------------------------------------------------------
// k6: sum split-K partials of sc, softmax over o, out = alpha2^T @ Xh
// 512 blocks (8-candidate tiles), XCD-grouped by b.
// ---------------------------------------------------------------------------
__global__ __launch_bounds__(256) void k6(const float* __restrict__ scP,
                                          const short* __restrict__ Xh,
                                          float* __restrict__ out) {
    __shared__ float al[8][64];
    const int tid = threadIdx.x;
    const int id = blockIdx.x;
    const int slot = id >> 3;
    const int b = (id & 7) * 2 + (slot >> 5);
    const int c0 = (slot & 31) * 8;
    const size_t ZS = (size_t)Bb * NCc * OSo;
    {
        const int cl = tid >> 5, t32 = tid & 31;
        const float* srow = scP + ((size_t)b * NCc + c0 + cl) * OSo;
        float v[2];
        float m = -1e30f;
        #pragma unroll
        for (int j = 0; j < 2; ++j) {
            const int o = t32 + j * 32;
            v[j] = srow[o] + srow[ZS + o] + srow[2 * ZS + o] + srow[3 * ZS + o];
            m = fmaxf(m, v[j]);
        }
        #pragma unroll
        for (int off = 16; off; off >>= 1) m = fmaxf(m, __shfl_xor(m, off, 32));
        float s = 0.f;
        #pragma unroll
        for (int j = 0; j < 2; ++j) { v[j] = __expf(v[j] - m); s += v[j]; }
        #pragma unroll
        for (int off = 16; off; off >>= 1) s += __shfl_xor(s, off, 32);
        float inv = 1.f / s;
        #pragma unroll
        for (int j = 0; j < 2; ++j) al[cl][t32 + j * 32] = v[j] * inv;
    }
    __syncthreads();
    const short* xb = Xh + (size_t)b * OSo * LABh;
    float acc[8][4] = {};
    for (int o = 0; o < OSo; ++o) {
        s4v xv = *(const s4v*)&xb[(size_t)o * LABh + tid * 4];
        const float x0 = b2f(xv[0]), x1 = b2f(xv[1]), x2 = b2f(xv[2]), x3 = b2f(xv[3]);
        #pragma unroll
        for (int c = 0; c < 8; ++c) {
            const float w = al[c][o];
            acc[c][0] += w * x0; acc[c][1] += w * x1; acc[c][2] += w * x2; acc[c][3] += w * x3;
        }
    }
    #pragma unroll
    for (int c = 0; c < 8; ++c) {
        float4 v; v.x = acc[c][0]; v.y = acc[c][1]; v.z = acc[c][2]; v.w = acc[c][3];
        *(float4*)&out[((size_t)b * NCc + c0 + c) * LABh + tid * 4] = v;
    }
}

// ---------------------------------------------------------------------------
extern "C" void kernel_launch(void* const* d_in, const int* in_sizes, int n_in,
                              void* d_out, int out_size, void* d_ws, size_t ws_size,
                              hipStream_t stream) {
    (void)in_sizes; (void)n_in; (void)out_size; (void)ws_size;
    const float* X      = (const float*)d_in[0];
    const int*   cand   = (const int*)  d_in[1];
    const float* a_w    = (const float*)d_in[2];
    const float* a_b    = (const float*)d_in[3];
    const float* h_w    = (const float*)d_in[4];
    const float* h_b    = (const float*)d_in[5];
    const float* gamma  = (const float*)d_in[6];
    const float* beta   = (const float*)d_in[7];
    const float* mean   = (const float*)d_in[8];
    const float* var    = (const float*)d_in[9];
    const float* labDesc= (const float*)d_in[10];
    float* outp = (float*)d_out;

    char* ws = (char*)d_ws;
    float* St   = (float*)ws;                               // 8MB: St (k1/k2) then XpP (k3, 2x4MB)
    float* XpP  = St;
    short* aBf  = (short*)(ws + ((size_t)8  << 20));        // 4MB alpha bf16
    short* Xh   = (short*)(ws + ((size_t)12 << 20));        // 2MB
    float* scP  = (float*)(ws + ((size_t)14 << 20));        // 4MB (4 split-K partials)
    short* a_wT = (short*)(ws + ((size_t)18 << 20));        // 128KB
    short* h_wT = (short*)(ws + ((size_t)19 << 20));        // 2MB

    k0 <<<272,          256, 0, stream>>>(h_w, a_w, h_wT, a_wT);
    k1 <<<dim3(32, 16), 256, 0, stream>>>(X, a_wT, a_b, St);
    k2 <<<Bb * OSo,     256, 0, stream>>>(St, aBf);
    k3 <<<512,          256, 0, stream>>>(X, aBf, XpP);
    k4 <<<dim3(16, 16), 256, 0, stream>>>(XpP, h_wT, h_b, gamma, beta, mean, var, Xh);
    k5 <<<dim3(16, 16), 256, 0, stream>>>(cand, labDesc, Xh, scP);
    k6 <<<512,          256, 0, stream>>>(scP, Xh, outp);
}

// Round 10
// 110.484 us; speedup vs baseline: 1.4485x; 1.4485x over previous
//
#include <hip/hip_runtime.h>
#include <hip/hip_bf16.h>
#include <math.h>

#define Bb   16
#define Ll   2048
#define Dd   1024
#define OSo  64
#define NCc  256
#define LABh 1024
#define BN_EPS 1e-5f

typedef short s8v  __attribute__((ext_vector_type(8)));   // 8 bf16 = 4 VGPR
typedef short s4v  __attribute__((ext_vector_type(4)));
typedef float f32x4 __attribute__((ext_vector_type(4)));

__device__ __forceinline__ short f2b(float f) {
    __hip_bfloat16 h = __float2bfloat16(f);
    short s;
    __builtin_memcpy(&s, &h, 2);
    return s;
}
__device__ __forceinline__ float b2f(short s) {
    union { unsigned u; float f; } v; v.u = ((unsigned)(unsigned short)s) << 16;
    return v.f;
}
// Barrier without vmcnt(0) drain: waits only this wave's LDS ops.
__device__ __forceinline__ void fastbar() {
    asm volatile("s_waitcnt lgkmcnt(0)\n\ts_barrier" ::: "memory");
}
// swizzled short-index into a [rows][64] bf16 LDS tile (row stride 128B).
__device__ __forceinline__ int swi(int row, int kElem) {
    return (row * 128 + ((kElem * 2) ^ ((row & 7) << 4))) >> 1;
}
__device__ __forceinline__ f32x4 MF(s8v a, s8v b, f32x4 c) {
    return __builtin_amdgcn_mfma_f32_16x16x32_bf16(a, b, c, 0, 0, 0);
}

// ---------------------------------------------------------------------------
// k0: transpose+convert weights.
// ---------------------------------------------------------------------------
__global__ __launch_bounds__(256) void k0(const float* __restrict__ h_w,
                                          const float* __restrict__ a_w,
                                          short* __restrict__ h_wT,
                                          short* __restrict__ a_wT) {
    __shared__ float t[64][68];
    const int tid = threadIdx.x, id = blockIdx.x;
    const float* src; short* dst; int srw, d0, y0;
    if (id < 256) { src = h_w; dst = h_wT; srw = LABh; d0 = (id & 15) * 64; y0 = (id >> 4) * 64; }
    else          { src = a_w; dst = a_wT; srw = OSo;  d0 = (id - 256) * 64; y0 = 0; }
    const int r = tid >> 2, cofs = (tid & 3) * 16;
    #pragma unroll
    for (int w = 0; w < 4; ++w) {
        float4 v = *(const float4*)&src[(size_t)(d0 + r) * srw + y0 + cofs + w * 4];
        t[r][cofs + w * 4 + 0] = v.x;
        t[r][cofs + w * 4 + 1] = v.y;
        t[r][cofs + w * 4 + 2] = v.z;
        t[r][cofs + w * 4 + 3] = v.w;
    }
    __syncthreads();
    s8v o0, o1;
    #pragma unroll
    for (int e = 0; e < 8; ++e) { o0[e] = f2b(t[cofs + e][r]); o1[e] = f2b(t[cofs + 8 + e][r]); }
    *(s8v*)&dst[(size_t)(y0 + r) * Dd + d0 + cofs]     = o0;
    *(s8v*)&dst[(size_t)(y0 + r) * Dd + d0 + cofs + 8] = o1;
}

// ---------------------------------------------------------------------------
// k1: StP[z][b][o][l] = (X@a_w)_partialK.  tile 64(l)x64(o), split-K=2
// (K=512 each), dbuf+prefetch, fastbar.  grid (32,16,2) = 1024 blocks
// (4 blocks/CU -> 4 waves/SIMD for latency hiding).
// ---------------------------------------------------------------------------
struct R1 { float4 x[4]; s8v w[2]; };

__global__ __launch_bounds__(256) void k1(const float* __restrict__ X,
                                          const short* __restrict__ a_wT,
                                          float* __restrict__ StP) {
    __shared__ __align__(16) char smem[32768];
    float (*ts)[65] = (float(*)[65])smem;                   // epilogue alias
    const int tid = threadIdx.x;
    const int lane = tid & 63, wave = tid >> 6;
    const int wm = wave >> 1, wn = wave & 1;
    const int b = blockIdx.y, l0 = blockIdx.x * 64;
    const int z = blockIdx.z, kbase = z * 512;
    const float* Xb = X + ((size_t)b * Ll + l0) * Dd;
    const int r = tid >> 2, kofs = (tid & 3) * 16;
    f32x4 acc[2][2] = {};
    R1 cur, nxt;
    #pragma unroll
    for (int w = 0; w < 2; ++w) {
        cur.x[2*w]   = *(const float4*)&Xb[(size_t)r * Dd + kbase + kofs + w * 8];
        cur.x[2*w+1] = *(const float4*)&Xb[(size_t)r * Dd + kbase + kofs + w * 8 + 4];
        cur.w[w]     = *(const s8v*)&a_wT[(size_t)r * Dd + kbase + kofs + w * 8];
    }
    #pragma unroll
    for (int t = 0; t < 8; ++t) {
        short* As = (short*)(smem + (t & 1) * 8192);
        short* Bs = (short*)(smem + 16384 + (t & 1) * 8192);
        #pragma unroll
        for (int w = 0; w < 2; ++w) {
            const float* f0 = (const float*)&cur.x[2*w];
            s8v s;
            s[0]=f2b(f0[0]); s[1]=f2b(f0[1]); s[2]=f2b(f0[2]); s[3]=f2b(f0[3]);
            s[4]=f2b(f0[4]); s[5]=f2b(f0[5]); s[6]=f2b(f0[6]); s[7]=f2b(f0[7]);
            *(s8v*)&As[swi(r, kofs + w * 8)] = s;
            *(s8v*)&Bs[swi(r, kofs + w * 8)] = cur.w[w];
        }
        fastbar();
        if (t < 7) {
            const int k0 = kbase + (t + 1) * 64;
            #pragma unroll
            for (int w = 0; w < 2; ++w) {
                nxt.x[2*w]   = *(const float4*)&Xb[(size_t)r * Dd + k0 + kofs + w * 8];
                nxt.x[2*w+1] = *(const float4*)&Xb[(size_t)r * Dd + k0 + kofs + w * 8 + 4];
                nxt.w[w]     = *(const s8v*)&a_wT[(size_t)r * Dd + k0 + kofs + w * 8];
            }
        }
        #pragma unroll
        for (int kk = 0; kk < 2; ++kk) {
            const int kb = kk * 32 + (lane >> 4) * 8;
            s8v a[2], bb[2];
            #pragma unroll
            for (int i = 0; i < 2; ++i)
                a[i] = *(const s8v*)&As[swi(wm * 32 + i * 16 + (lane & 15), kb)];
            #pragma unroll
            for (int j = 0; j < 2; ++j)
                bb[j] = *(const s8v*)&Bs[swi(wn * 32 + j * 16 + (lane & 15), kb)];
            #pragma unroll
            for (int i = 0; i < 2; ++i)
                #pragma unroll
                for (int j = 0; j < 2; ++j)
                    acc[i][j] = MF(a[i], bb[j], acc[i][j]);
        }
        if (t < 7) cur = nxt;
    }
    __syncthreads();                                        // before ts alias writes
    #pragma unroll
    for (int i = 0; i < 2; ++i)
        #pragma unroll
        for (int j = 0; j < 2; ++j)
            #pragma unroll
            for (int rr = 0; rr < 4; ++rr)
                ts[wm * 32 + i * 16 + (lane >> 4) * 4 + rr][wn * 32 + j * 16 + (lane & 15)] = acc[i][j][rr];
    __syncthreads();
    const int o = tid >> 2, lofs = (tid & 3) * 16;
    float* Sp = StP + (size_t)z * ((size_t)Bb * OSo * Ll)
                    + ((size_t)b * OSo + o) * Ll + l0 + lofs;
    #pragma unroll
    for (int w = 0; w < 4; ++w) {
        float4 v;
        v.x = ts[lofs + w * 4 + 0][o];
        v.y = ts[lofs + w * 4 + 1][o];
        v.z = ts[lofs + w * 4 + 2][o];
        v.w = ts[lofs + w * 4 + 3][o];
        *(float4*)&Sp[w * 4] = v;
    }
}

// ---------------------------------------------------------------------------
// k2: sum 2 St partials + a_b, softmax over L, write alpha bf16
// ---------------------------------------------------------------------------
__global__ __launch_bounds__(256) void k2(const float* __restrict__ StP,
                                          const float* __restrict__ a_b,
                                          short* __restrict__ aBf) {
    __shared__ float row[Ll];
    __shared__ float red[8];
    const size_t ZS = (size_t)Bb * OSo * Ll;
    const float* p0 = StP + (size_t)blockIdx.x * Ll;
    const float* p1 = p0 + ZS;
    short* ab = aBf + (size_t)blockIdx.x * Ll;
    const int tid = threadIdx.x;
    const int wave = tid >> 6, lane = tid & 63;
    const float bias = a_b[blockIdx.x & (OSo - 1)];
    float m = -1e30f;
    for (int i = tid; i < Ll; i += 256) {
        float v = p0[i] + p1[i] + bias;
        row[i] = v; m = fmaxf(m, v);
    }
    #pragma unroll
    for (int off = 32; off; off >>= 1) m = fmaxf(m, __shfl_down(m, off));
    if (lane == 0) red[wave] = m;
    __syncthreads();
    if (tid == 0) red[4] = fmaxf(fmaxf(red[0], red[1]), fmaxf(red[2], red[3]));
    __syncthreads();
    const float M = red[4];
    float s = 0.f;
    for (int i = tid; i < Ll; i += 256) { float e = __expf(row[i] - M); row[i] = e; s += e; }
    __syncthreads();
    #pragma unroll
    for (int off = 32; off; off >>= 1) s += __shfl_down(s, off);
    if (lane == 0) red[wave] = s;
    __syncthreads();
    if (tid == 0) red[4] = 1.f / (red[0] + red[1] + red[2] + red[3]);
    __syncthreads();
    const float inv = red[4];
    for (int i = tid; i < Ll; i += 256) ab[i] = f2b(row[i] * inv);
}

// ---------------------------------------------------------------------------
// k3: Xp_part[z] = alpha_half @ X_half.  tile 64(o)x64(d), split-K=2,
// dbuf+prefetch+fastbar.  512 blocks, XCD-grouped by b.  (round-8 exact)
// ---------------------------------------------------------------------------
struct R3 { s8v al[2]; float4 xv[4]; };

__global__ __launch_bounds__(256) void k3(const float* __restrict__ X,
                                          const short* __restrict__ aBf,
                                          float* __restrict__ XpP) {
    __shared__ __align__(16) char smem[32768];
    float (*ts)[68] = (float(*)[68])smem;                   // epilogue alias
    const int tid = threadIdx.x;
    const int lane = tid & 63, wave = tid >> 6;
    const int wm = wave >> 1, wn = wave & 1;
    const int id = blockIdx.x;
    const int slot = id >> 3;
    const int b = (id & 7) * 2 + (slot >> 5);
    const int inner = slot & 31;
    const int dt = inner & 15, z = inner >> 4;
    const int d0 = dt * 64;
    const float* Xb = X + (size_t)b * Ll * Dd;
    const short* ab = aBf + (size_t)b * OSo * Ll;
    float* outP = XpP + (size_t)z * ((size_t)Bb * OSo * Dd);
    f32x4 acc[2][2] = {};
    const int arow = tid >> 2, akofs = (tid & 3) * 16;
    const int lq = tid & 15, dq = tid >> 4;
    const int lbase = z * 1024;
    R3 cur, nxt;
    #pragma unroll
    for (int w = 0; w < 2; ++w)
        cur.al[w] = *(const s8v*)&ab[(size_t)arow * Ll + lbase + akofs + w * 8];
    #pragma unroll
    for (int i = 0; i < 4; ++i)
        cur.xv[i] = *(const float4*)&Xb[(size_t)(lbase + lq * 4 + i) * Dd + d0 + dq * 4];
    #pragma unroll
    for (int t = 0; t < 16; ++t) {
        short* Aal = (short*)(smem + (t & 1) * 8192);
        short* Xs  = (short*)(smem + 16384 + (t & 1) * 8192);
        #pragma unroll
        for (int w = 0; w < 2; ++w)
            *(s8v*)&Aal[swi(arow, akofs + w * 8)] = cur.al[w];
        {
            const float* f = (const float*)cur.xv;          // f[i*4+j] = X[l=lq*4+i][d=dq*4+j]
            #pragma unroll
            for (int j = 0; j < 4; ++j) {
                const int rowd = dq * 4 + j;
                s4v sj;
                sj[0] = f2b(f[0 * 4 + j]);
                sj[1] = f2b(f[1 * 4 + j]);
                sj[2] = f2b(f[2 * 4 + j]);
                sj[3] = f2b(f[3 * 4 + j]);
                *(s4v*)&Xs[swi(rowd, lq * 4)] = sj;
            }
        }
        fastbar();
        if (t < 15) {
            const int l0 = lbase + (t + 1) * 64;
            #pragma unroll
            for (int w = 0; w < 2; ++w)
                nxt.al[w] = *(const s8v*)&ab[(size_t)arow * Ll + l0 + akofs + w * 8];
            #pragma unroll
            for (int i = 0; i < 4; ++i)
                nxt.xv[i] = *(const float4*)&Xb[(size_t)(l0 + lq * 4 + i) * Dd + d0 + dq * 4];
        }
        #pragma unroll
        for (int kk = 0; kk < 2; ++kk) {
            const int kb = kk * 32 + (lane >> 4) * 8;
            s8v a[2], bb[2];
            #pragma unroll
            for (int i = 0; i < 2; ++i)
                a[i] = *(const s8v*)&Aal[swi(wm * 32 + i * 16 + (lane & 15), kb)];
            #pragma unroll
            for (int j = 0; j < 2; ++j)
                bb[j] = *(const s8v*)&Xs[swi(wn * 32 + j * 16 + (lane & 15), kb)];
            #pragma unroll
            for (int i = 0; i < 2; ++i)
                #pragma unroll
                for (int j = 0; j < 2; ++j)
                    acc[i][j] = MF(a[i], bb[j], acc[i][j]);
        }
        if (t < 15) cur = nxt;
    }
    __syncthreads();
    #pragma unroll
    for (int i = 0; i < 2; ++i)
        #pragma unroll
        for (int j = 0; j < 2; ++j)
            #pragma unroll
            for (int rr = 0; rr < 4; ++rr)
                ts[wm * 32 + i * 16 + (lane >> 4) * 4 + rr][wn * 32 + j * 16 + (lane & 15)] = acc[i][j][rr];
    __syncthreads();
    const int o = tid >> 2, dofs = (tid & 3) * 16;
    float* op = outP + ((size_t)b * OSo + o) * Dd + d0 + dofs;
    #pragma unroll
    for (int w = 0; w < 4; ++w)
        *(float4*)&op[w * 4] = *(float4*)&ts[o][dofs + w * 4];
}

// ---------------------------------------------------------------------------
// k4: Xh = bf16(relu(BN((XpP0+XpP1)@h_w + h_b)))  tile 64x64, dbuf+prefetch
// (round-8 exact)
// ---------------------------------------------------------------------------
struct R4 { float4 p[8]; s8v w[2]; };

__global__ __launch_bounds__(256) void k4(const float* __restrict__ XpP,
                                          const short* __restrict__ h_wT,
                                          const float* __restrict__ h_b,
                                          const float* __restrict__ gamma,
                                          const float* __restrict__ beta,
                                          const float* __restrict__ mean,
                                          const float* __restrict__ var,
                                          short* __restrict__ Xh) {
    __shared__ __align__(16) char smem[32768];
    short* tsb = (short*)smem;                              // epilogue alias [64][64]
    const int tid = threadIdx.x, lane = tid & 63, wave = tid >> 6;
    const int wm = wave >> 1, wn = wave & 1;
    const int h0 = blockIdx.x * 64, m0 = blockIdx.y * 64;
    const int r = tid >> 2, kofs = (tid & 3) * 16;
    const size_t ZS = (size_t)Bb * OSo * Dd;
    f32x4 acc[2][2] = {};
    R4 cur, nxt;
    #pragma unroll
    for (int w = 0; w < 2; ++w) {
        const float* p0 = XpP + (size_t)(m0 + r) * Dd + kofs + w * 8;
        cur.p[w*4+0] = *(const float4*)&p0[0];
        cur.p[w*4+1] = *(const float4*)&p0[4];
        cur.p[w*4+2] = *(const float4*)&p0[ZS];
        cur.p[w*4+3] = *(const float4*)&p0[ZS + 4];
        cur.w[w]     = *(const s8v*)&h_wT[(size_t)(h0 + r) * Dd + kofs + w * 8];
    }
    #pragma unroll
    for (int t = 0; t < 16; ++t) {
        short* As = (short*)(smem + (t & 1) * 8192);
        short* Bs = (short*)(smem + 16384 + (t & 1) * 8192);
        #pragma unroll
        for (int w = 0; w < 2; ++w) {
            const float* f0 = (const float*)&cur.p[w*4];
            const float* f1 = (const float*)&cur.p[w*4+2];
            s8v s;
            #pragma unroll
            for (int e = 0; e < 8; ++e) s[e] = f2b(f0[e] + f1[e]);
            *(s8v*)&As[swi(r, kofs + w * 8)] = s;
            *(s8v*)&Bs[swi(r, kofs + w * 8)] = cur.w[w];
        }
        fastbar();
        if (t < 15) {
            const int k0 = (t + 1) * 64;
            #pragma unroll
            for (int w = 0; w < 2; ++w) {
                const float* p0 = XpP + (size_t)(m0 + r) * Dd + k0 + kofs + w * 8;
                nxt.p[w*4+0] = *(const float4*)&p0[0];
                nxt.p[w*4+1] = *(const float4*)&p0[4];
                nxt.p[w*4+2] = *(const float4*)&p0[ZS];
                nxt.p[w*4+3] = *(const float4*)&p0[ZS + 4];
                nxt.w[w]     = *(const s8v*)&h_wT[(size_t)(h0 + r) * Dd + k0 + kofs + w * 8];
            }
        }
        #pragma unroll
        for (int kk = 0; kk < 2; ++kk) {
            const int kb = kk * 32 + (lane >> 4) * 8;
            s8v a[2], bb[2];
            #pragma unroll
            for (int i = 0; i < 2; ++i)
                a[i] = *(const s8v*)&As[swi(wm * 32 + i * 16 + (lane & 15), kb)];
            #pragma unroll
            for (int j = 0; j < 2; ++j)
                bb[j] = *(const s8v*)&Bs[swi(wn * 32 + j * 16 + (lane & 15), kb)];
            #pragma unroll
            for (int i = 0; i < 2; ++i)
                #pragma unroll
                for (int j = 0; j < 2; ++j)
                    acc[i][j] = MF(a[i], bb[j], acc[i][j]);
        }
        if (t < 15) cur = nxt;
    }
    __syncthreads();
    #pragma unroll
    for (int j = 0; j < 2; ++j) {
        const int h = h0 + wn * 32 + j * 16 + (lane & 15);
        const float sc = gamma[h] * rsqrtf(var[h] + BN_EPS);
        const float of = (h_b[h] - mean[h]) * sc + beta[h];
        #pragma unroll
        for (int i = 0; i < 2; ++i)
            #pragma unroll
            for (int rr = 0; rr < 4; ++rr) {
                const int ml = wm * 32 + i * 16 + (lane >> 4) * 4 + rr;
                tsb[ml * 64 + wn * 32 + j * 16 + (lane & 15)] = f2b(fmaxf(0.f, acc[i][j][rr] * sc + of));
            }
    }
    __syncthreads();
    #pragma unroll
    for (int w = 0; w < 2; ++w)
        *(s8v*)&Xh[(size_t)(m0 + r) * LABh + h0 + kofs + w * 8] = *(const s8v*)&tsb[r * 64 + kofs + w * 8];
}

// ---------------------------------------------------------------------------
// k5: scP[z][b][c][o] partial over K range z.  tile 64(c)x64(o), split-K=4,
// dbuf+prefetch+fastbar.  (round-8 exact)
// ---------------------------------------------------------------------------
struct R5 { float4 ld[4]; s8v xh[2]; };

__global__ __launch_bounds__(256) void k5(const int* __restrict__ cand,
                                          const float* __restrict__ labD,
                                          const short* __restrict__ Xh,
                                          float* __restrict__ scP) {
    __shared__ __align__(16) char smem[33024];
    float (*ts)[68] = (float(*)[68])smem;
    int* cidx = (int*)(smem + 32768);
    const int tid = threadIdx.x, lane = tid & 63, wave = tid >> 6;
    const int wm = wave >> 1, wn = wave & 1;
    const int b = blockIdx.y;
    const int ct = blockIdx.x & 3, z = blockIdx.x >> 2;
    const int c0 = ct * 64;
    const int kbase = z * 256;
    if (tid < 64) cidx[tid] = cand[b * NCc + c0 + tid];
    __syncthreads();
    const int r = tid >> 2, kofs = (tid & 3) * 16;
    const int ci = cidx[r];
    const float* lrow = labD + (size_t)ci * LABh + kbase;
    const short* xrow = Xh + (size_t)(b * OSo + r) * LABh + kbase;
    f32x4 acc[2][2] = {};
    R5 cur, nxt;
    #pragma unroll
    for (int w = 0; w < 2; ++w) {
        cur.ld[2*w]   = *(const float4*)&lrow[kofs + w * 8];
        cur.ld[2*w+1] = *(const float4*)&lrow[kofs + w * 8 + 4];
        cur.xh[w]     = *(const s8v*)&xrow[kofs + w * 8];
    }
    #pragma unroll
    for (int t = 0; t < 4; ++t) {
        short* As = (short*)(smem + (t & 1) * 8192);
        short* Bs = (short*)(smem + 16384 + (t & 1) * 8192);
        #pragma unroll
        for (int w = 0; w < 2; ++w) {
            const float* f0 = (const float*)&cur.ld[2*w];
            s8v s;
            #pragma unroll
            for (int e = 0; e < 8; ++e) s[e] = f2b(f0[e]);
            *(s8v*)&As[swi(r, kofs + w * 8)] = s;
            *(s8v*)&Bs[swi(r, kofs + w * 8)] = cur.xh[w];
        }
        fastbar();
        if (t < 3) {
            const int k0 = (t + 1) * 64;
            #pragma unroll
            for (int w = 0; w < 2; ++w) {
                nxt.ld[2*w]   = *(const float4*)&lrow[k0 + kofs + w * 8];
                nxt.ld[2*w+1] = *(const float4*)&lrow[k0 + kofs + w * 8 + 4];
                nxt.xh[w]     = *(const s8v*)&xrow[k0 + kofs + w * 8];
            }
        }
        #pragma unroll
        for (int kk = 0; kk < 2; ++kk) {
            const int kb = kk * 32 + (lane >> 4) * 8;
            s8v a[2], bb[2];
            #pragma unroll
            for (int i = 0; i < 2; ++i)
                a[i] = *(const s8v*)&As[swi(wm * 32 + i * 16 + (lane & 15), kb)];
            #pragma unroll
            for (int j = 0; j < 2; ++j)
                bb[j] = *(const s8v*)&Bs[swi(wn * 32 + j * 16 + (lane & 15), kb)];
            #pragma unroll
            for (int i = 0; i < 2; ++i)
                #pragma unroll
                for (int j = 0; j < 2; ++j)
                    acc[i][j] = MF(a[i], bb[j], acc[i][j]);
        }
        if (t < 3) cur = nxt;
    }
    __syncthreads();
    #pragma unroll
    for (int i = 0; i < 2; ++i)
        #pragma unroll
        for (int j = 0; j < 2; ++j)
            #pragma unroll
            for (int rr = 0; rr < 4; ++rr)
                ts[wm * 32 + i * 16 + (lane >> 4) * 4 + rr][wn * 32 + j * 16 + (lane & 15)] = acc[i][j][rr];
    __syncthreads();
    const int oofs = (tid & 3) * 16;
    float* sp = scP + (size_t)z * ((size_t)Bb * NCc * OSo)
                    + ((size_t)b * NCc + c0 + r) * OSo + oofs;
    #pragma unroll
    for (int w = 0; w < 4; ++w)
        *(float4*)&sp[w * 4] = *(float4*)&ts[r][oofs + w * 4];
}

// ---------------------------------------------------------------------------
// k6: sum split-K partials of sc, softmax over o, out = alpha2^T @ Xh
// 512 blocks (8-candidate tiles), XCD-grouped by b.  (round-8 exact)
// ---------------------------------------------------------------------------
__global__ __launch_bounds__(256) void k6(const float* __restrict__ scP,
                                          const short* __restrict__ Xh,
                                          float* __restrict__ out) {
    __shared__ float al[8][64];
    const int tid = threadIdx.x;
    const int id = blockIdx.x;
    const int slot = id >> 3;
    const int b = (id & 7) * 2 + (slot >> 5);
    const int c0 = (slot & 31) * 8;
    const size_t ZS = (size_t)Bb * NCc * OSo;
    {
        const int cl = tid >> 5, t32 = tid & 31;
        const float* srow = scP + ((size_t)b * NCc + c0 + cl) * OSo;
        float v[2];
        float m = -1e30f;
        #pragma unroll
        for (int j = 0; j < 2; ++j) {
            const int o = t32 + j * 32;
            v[j] = srow[o] + srow[ZS + o] + srow[2 * ZS + o] + srow[3 * ZS + o];
            m = fmaxf(m, v[j]);
        }
        #pragma unroll
        for (int off = 16; off; off >>= 1) m = fmaxf(m, __shfl_xor(m, off, 32));
        float s = 0.f;
        #pragma unroll
        for (int j = 0; j < 2; ++j) { v[j] = __expf(v[j] - m); s += v[j]; }
        #pragma unroll
        for (int off = 16; off; off >>= 1) s += __shfl_xor(s, off, 32);
        float inv = 1.f / s;
        #pragma unroll
        for (int j = 0; j < 2; ++j) al[cl][t32 + j * 32] = v[j] * inv;
    }
    __syncthreads();
    const short* xb = Xh + (size_t)b * OSo * LABh;
    float acc[8][4] = {};
    for (int o = 0; o < OSo; ++o) {
        s4v xv = *(const s4v*)&xb[(size_t)o * LABh + tid * 4];
        const float x0 = b2f(xv[0]), x1 = b2f(xv[1]), x2 = b2f(xv[2]), x3 = b2f(xv[3]);
        #pragma unroll
        for (int c = 0; c < 8; ++c) {
            const float w = al[c][o];
            acc[c][0] += w * x0; acc[c][1] += w * x1; acc[c][2] += w * x2; acc[c][3] += w * x3;
        }
    }
    #pragma unroll
    for (int c = 0; c < 8; ++c) {
        float4 v; v.x = acc[c][0]; v.y = acc[c][1]; v.z = acc[c][2]; v.w = acc[c][3];
        *(float4*)&out[((size_t)b * NCc + c0 + c) * LABh + tid * 4] = v;
    }
}

// ---------------------------------------------------------------------------
extern "C" void kernel_launch(void* const* d_in, const int* in_sizes, int n_in,
                              void* d_out, int out_size, void* d_ws, size_t ws_size,
                              hipStream_t stream) {
    (void)in_sizes; (void)n_in; (void)out_size; (void)ws_size;
    const float* X      = (const float*)d_in[0];
    const int*   cand   = (const int*)  d_in[1];
    const float* a_w    = (const float*)d_in[2];
    const float* a_b    = (const float*)d_in[3];
    const float* h_w    = (const float*)d_in[4];
    const float* h_b    = (const float*)d_in[5];
    const float* gamma  = (const float*)d_in[6];
    const float* beta   = (const float*)d_in[7];
    const float* mean   = (const float*)d_in[8];
    const float* var    = (const float*)d_in[9];
    const float* labDesc= (const float*)d_in[10];
    float* outp = (float*)d_out;

    char* ws = (char*)d_ws;
    float* StP  = (float*)ws;                               // 16MB (2 partials); XpP aliases after k2
    float* XpP  = (float*)ws;                               // 8MB (2 partials)
    short* aBf  = (short*)(ws + ((size_t)16 << 20));        // 4MB alpha bf16
    short* Xh   = (short*)(ws + ((size_t)20 << 20));        // 2MB
    float* scP  = (float*)(ws + ((size_t)22 << 20));        // 4MB (4 split-K partials)
    short* a_wT = (short*)(ws + ((size_t)26 << 20));        // 128KB
    short* h_wT = (short*)(ws + ((size_t)27 << 20));        // 2MB

    k0 <<<272,              256, 0, stream>>>(h_w, a_w, h_wT, a_wT);
    k1 <<<dim3(32, 16, 2),  256, 0, stream>>>(X, a_wT, StP);
    k2 <<<Bb * OSo,         256, 0, stream>>>(StP, a_b, aBf);
    k3 <<<512,              256, 0, stream>>>(X, aBf, XpP);
    k4 <<<dim3(16, 16),     256, 0, stream>>>(XpP, h_wT, h_b, gamma, beta, mean, var, Xh);
    k5 <<<dim3(16, 16),     256, 0, stream>>>(cand, labDesc, Xh, scP);
    k6 <<<512,              256, 0, stream>>>(scP, Xh, outp);
}

// Round 11
// 106.156 us; speedup vs baseline: 1.5076x; 1.0408x over previous
//
#include <hip/hip_runtime.h>
#include <hip/hip_bf16.h>
#include <math.h>

#define Bb   16
#define Ll   2048
#define Dd   1024
#define OSo  64
#define NCc  256
#define LABh 1024
#define BN_EPS 1e-5f

typedef short s8v  __attribute__((ext_vector_type(8)));   // 8 bf16 = 4 VGPR
typedef short s4v  __attribute__((ext_vector_type(4)));
typedef float f32x4 __attribute__((ext_vector_type(4)));

__device__ __forceinline__ short f2b(float f) {
    __hip_bfloat16 h = __float2bfloat16(f);
    short s;
    __builtin_memcpy(&s, &h, 2);
    return s;
}
__device__ __forceinline__ float b2f(short s) {
    union { unsigned u; float f; } v; v.u = ((unsigned)(unsigned short)s) << 16;
    return v.f;
}
// Barrier without vmcnt(0) drain: waits only this wave's LDS ops.
__device__ __forceinline__ void fastbar() {
    asm volatile("s_waitcnt lgkmcnt(0)\n\ts_barrier" ::: "memory");
}
// swizzled short-index into a [rows][64] bf16 LDS tile (row stride 128B).
__device__ __forceinline__ int swi(int row, int kElem) {
    return (row * 128 + ((kElem * 2) ^ ((row & 7) << 4))) >> 1;
}
__device__ __forceinline__ f32x4 MF(s8v a, s8v b, f32x4 c) {
    return __builtin_amdgcn_mfma_f32_16x16x32_bf16(a, b, c, 0, 0, 0);
}

// ---------------------------------------------------------------------------
// k0: transpose+convert weights.
// ---------------------------------------------------------------------------
__global__ __launch_bounds__(256) void k0(const float* __restrict__ h_w,
                                          const float* __restrict__ a_w,
                                          short* __restrict__ h_wT,
                                          short* __restrict__ a_wT) {
    __shared__ float t[64][68];
    const int tid = threadIdx.x, id = blockIdx.x;
    const float* src; short* dst; int srw, d0, y0;
    if (id < 256) { src = h_w; dst = h_wT; srw = LABh; d0 = (id & 15) * 64; y0 = (id >> 4) * 64; }
    else          { src = a_w; dst = a_wT; srw = OSo;  d0 = (id - 256) * 64; y0 = 0; }
    const int r = tid >> 2, cofs = (tid & 3) * 16;
    #pragma unroll
    for (int w = 0; w < 4; ++w) {
        float4 v = *(const float4*)&src[(size_t)(d0 + r) * srw + y0 + cofs + w * 4];
        t[r][cofs + w * 4 + 0] = v.x;
        t[r][cofs + w * 4 + 1] = v.y;
        t[r][cofs + w * 4 + 2] = v.z;
        t[r][cofs + w * 4 + 3] = v.w;
    }
    __syncthreads();
    s8v o0, o1;
    #pragma unroll
    for (int e = 0; e < 8; ++e) { o0[e] = f2b(t[cofs + e][r]); o1[e] = f2b(t[cofs + 8 + e][r]); }
    *(s8v*)&dst[(size_t)(y0 + r) * Dd + d0 + cofs]     = o0;
    *(s8v*)&dst[(size_t)(y0 + r) * Dd + d0 + cofs + 8] = o1;
}

// ---------------------------------------------------------------------------
// k1: StP[z][b][o][l] = (X@a_w)_partialK.  tile 64(l)x64(o), split-K=2,
// dbuf+prefetch+fastbar.  grid (32,16,2).  (round-10 exact)
// ---------------------------------------------------------------------------
struct R1 { float4 x[4]; s8v w[2]; };

__global__ __launch_bounds__(256) void k1(const float* __restrict__ X,
                                          const short* __restrict__ a_wT,
                                          float* __restrict__ StP) {
    __shared__ __align__(16) char smem[32768];
    float (*ts)[65] = (float(*)[65])smem;                   // epilogue alias
    const int tid = threadIdx.x;
    const int lane = tid & 63, wave = tid >> 6;
    const int wm = wave >> 1, wn = wave & 1;
    const int b = blockIdx.y, l0 = blockIdx.x * 64;
    const int z = blockIdx.z, kbase = z * 512;
    const float* Xb = X + ((size_t)b * Ll + l0) * Dd;
    const int r = tid >> 2, kofs = (tid & 3) * 16;
    f32x4 acc[2][2] = {};
    R1 cur, nxt;
    #pragma unroll
    for (int w = 0; w < 2; ++w) {
        cur.x[2*w]   = *(const float4*)&Xb[(size_t)r * Dd + kbase + kofs + w * 8];
        cur.x[2*w+1] = *(const float4*)&Xb[(size_t)r * Dd + kbase + kofs + w * 8 + 4];
        cur.w[w]     = *(const s8v*)&a_wT[(size_t)r * Dd + kbase + kofs + w * 8];
    }
    #pragma unroll
    for (int t = 0; t < 8; ++t) {
        short* As = (short*)(smem + (t & 1) * 8192);
        short* Bs = (short*)(smem + 16384 + (t & 1) * 8192);
        #pragma unroll
        for (int w = 0; w < 2; ++w) {
            const float* f0 = (const float*)&cur.x[2*w];
            s8v s;
            s[0]=f2b(f0[0]); s[1]=f2b(f0[1]); s[2]=f2b(f0[2]); s[3]=f2b(f0[3]);
            s[4]=f2b(f0[4]); s[5]=f2b(f0[5]); s[6]=f2b(f0[6]); s[7]=f2b(f0[7]);
            *(s8v*)&As[swi(r, kofs + w * 8)] = s;
            *(s8v*)&Bs[swi(r, kofs + w * 8)] = cur.w[w];
        }
        fastbar();
        if (t < 7) {
            const int k0 = kbase + (t + 1) * 64;
            #pragma unroll
            for (int w = 0; w < 2; ++w) {
                nxt.x[2*w]   = *(const float4*)&Xb[(size_t)r * Dd + k0 + kofs + w * 8];
                nxt.x[2*w+1] = *(const float4*)&Xb[(size_t)r * Dd + k0 + kofs + w * 8 + 4];
                nxt.w[w]     = *(const s8v*)&a_wT[(size_t)r * Dd + k0 + kofs + w * 8];
            }
        }
        #pragma unroll
        for (int kk = 0; kk < 2; ++kk) {
            const int kb = kk * 32 + (lane >> 4) * 8;
            s8v a[2], bb[2];
            #pragma unroll
            for (int i = 0; i < 2; ++i)
                a[i] = *(const s8v*)&As[swi(wm * 32 + i * 16 + (lane & 15), kb)];
            #pragma unroll
            for (int j = 0; j < 2; ++j)
                bb[j] = *(const s8v*)&Bs[swi(wn * 32 + j * 16 + (lane & 15), kb)];
            #pragma unroll
            for (int i = 0; i < 2; ++i)
                #pragma unroll
                for (int j = 0; j < 2; ++j)
                    acc[i][j] = MF(a[i], bb[j], acc[i][j]);
        }
        if (t < 7) cur = nxt;
    }
    __syncthreads();                                        // before ts alias writes
    #pragma unroll
    for (int i = 0; i < 2; ++i)
        #pragma unroll
        for (int j = 0; j < 2; ++j)
            #pragma unroll
            for (int rr = 0; rr < 4; ++rr)
                ts[wm * 32 + i * 16 + (lane >> 4) * 4 + rr][wn * 32 + j * 16 + (lane & 15)] = acc[i][j][rr];
    __syncthreads();
    const int o = tid >> 2, lofs = (tid & 3) * 16;
    float* Sp = StP + (size_t)z * ((size_t)Bb * OSo * Ll)
                    + ((size_t)b * OSo + o) * Ll + l0 + lofs;
    #pragma unroll
    for (int w = 0; w < 4; ++w) {
        float4 v;
        v.x = ts[lofs + w * 4 + 0][o];
        v.y = ts[lofs + w * 4 + 1][o];
        v.z = ts[lofs + w * 4 + 2][o];
        v.w = ts[lofs + w * 4 + 3][o];
        *(float4*)&Sp[w * 4] = v;
    }
}

// ---------------------------------------------------------------------------
// k2: sum 2 St partials + a_b, softmax over L, write alpha bf16.
// float4-vectorized loads/stores (G13).
// ---------------------------------------------------------------------------
__global__ __launch_bounds__(256) void k2(const float* __restrict__ StP,
                                          const float* __restrict__ a_b,
                                          short* __restrict__ aBf) {
    __shared__ float row[Ll];
    __shared__ float red[8];
    const size_t ZS = (size_t)Bb * OSo * Ll;
    const float* p0 = StP + (size_t)blockIdx.x * Ll;
    const float* p1 = p0 + ZS;
    short* ab = aBf + (size_t)blockIdx.x * Ll;
    const int tid = threadIdx.x;
    const int wave = tid >> 6, lane = tid & 63;
    const float bias = a_b[blockIdx.x & (OSo - 1)];
    const int base = tid * 4;
    float m = -1e30f;
    #pragma unroll
    for (int i = base; i < Ll; i += 1024) {
        float4 a = *(const float4*)&p0[i];
        float4 c = *(const float4*)&p1[i];
        float4 v;
        v.x = a.x + c.x + bias; v.y = a.y + c.y + bias;
        v.z = a.z + c.z + bias; v.w = a.w + c.w + bias;
        *(float4*)&row[i] = v;
        m = fmaxf(m, fmaxf(fmaxf(v.x, v.y), fmaxf(v.z, v.w)));
    }
    #pragma unroll
    for (int off = 32; off; off >>= 1) m = fmaxf(m, __shfl_down(m, off));
    if (lane == 0) red[wave] = m;
    __syncthreads();
    if (tid == 0) red[4] = fmaxf(fmaxf(red[0], red[1]), fmaxf(red[2], red[3]));
    __syncthreads();
    const float M = red[4];
    float s = 0.f;
    #pragma unroll
    for (int i = base; i < Ll; i += 1024) {
        float4 v = *(const float4*)&row[i];
        v.x = __expf(v.x - M); v.y = __expf(v.y - M);
        v.z = __expf(v.z - M); v.w = __expf(v.w - M);
        *(float4*)&row[i] = v;
        s += (v.x + v.y) + (v.z + v.w);
    }
    __syncthreads();
    #pragma unroll
    for (int off = 32; off; off >>= 1) s += __shfl_down(s, off);
    if (lane == 0) red[wave] = s;
    __syncthreads();
    if (tid == 0) red[4] = 1.f / (red[0] + red[1] + red[2] + red[3]);
    __syncthreads();
    const float inv = red[4];
    #pragma unroll
    for (int i = base; i < Ll; i += 1024) {
        float4 v = *(const float4*)&row[i];
        s4v o;
        o[0] = f2b(v.x * inv); o[1] = f2b(v.y * inv);
        o[2] = f2b(v.z * inv); o[3] = f2b(v.w * inv);
        *(s4v*)&ab[i] = o;
    }
}

// ---------------------------------------------------------------------------
// k3: Xp_part[z] = alpha_half @ X_half.  tile 64(o)x64(d), split-K=2,
// dbuf+prefetch+fastbar.  512 blocks, XCD-grouped by b.  (round-10 exact)
// ---------------------------------------------------------------------------
struct R3 { s8v al[2]; float4 xv[4]; };

__global__ __launch_bounds__(256) void k3(const float* __restrict__ X,
                                          const short* __restrict__ aBf,
                                          float* __restrict__ XpP) {
    __shared__ __align__(16) char smem[32768];
    float (*ts)[68] = (float(*)[68])smem;                   // epilogue alias
    const int tid = threadIdx.x;
    const int lane = tid & 63, wave = tid >> 6;
    const int wm = wave >> 1, wn = wave & 1;
    const int id = blockIdx.x;
    const int slot = id >> 3;
    const int b = (id & 7) * 2 + (slot >> 5);
    const int inner = slot & 31;
    const int dt = inner & 15, z = inner >> 4;
    const int d0 = dt * 64;
    const float* Xb = X + (size_t)b * Ll * Dd;
    const short* ab = aBf + (size_t)b * OSo * Ll;
    float* outP = XpP + (size_t)z * ((size_t)Bb * OSo * Dd);
    f32x4 acc[2][2] = {};
    const int arow = tid >> 2, akofs = (tid & 3) * 16;
    const int lq = tid & 15, dq = tid >> 4;
    const int lbase = z * 1024;
    R3 cur, nxt;
    #pragma unroll
    for (int w = 0; w < 2; ++w)
        cur.al[w] = *(const s8v*)&ab[(size_t)arow * Ll + lbase + akofs + w * 8];
    #pragma unroll
    for (int i = 0; i < 4; ++i)
        cur.xv[i] = *(const float4*)&Xb[(size_t)(lbase + lq * 4 + i) * Dd + d0 + dq * 4];
    #pragma unroll
    for (int t = 0; t < 16; ++t) {
        short* Aal = (short*)(smem + (t & 1) * 8192);
        short* Xs  = (short*)(smem + 16384 + (t & 1) * 8192);
        #pragma unroll
        for (int w = 0; w < 2; ++w)
            *(s8v*)&Aal[swi(arow, akofs + w * 8)] = cur.al[w];
        {
            const float* f = (const float*)cur.xv;          // f[i*4+j] = X[l=lq*4+i][d=dq*4+j]
            #pragma unroll
            for (int j = 0; j < 4; ++j) {
                const int rowd = dq * 4 + j;
                s4v sj;
                sj[0] = f2b(f[0 * 4 + j]);
                sj[1] = f2b(f[1 * 4 + j]);
                sj[2] = f2b(f[2 * 4 + j]);
                sj[3] = f2b(f[3 * 4 + j]);
                *(s4v*)&Xs[swi(rowd, lq * 4)] = sj;
            }
        }
        fastbar();
        if (t < 15) {
            const int l0 = lbase + (t + 1) * 64;
            #pragma unroll
            for (int w = 0; w < 2; ++w)
                nxt.al[w] = *(const s8v*)&ab[(size_t)arow * Ll + l0 + akofs + w * 8];
            #pragma unroll
            for (int i = 0; i < 4; ++i)
                nxt.xv[i] = *(const float4*)&Xb[(size_t)(l0 + lq * 4 + i) * Dd + d0 + dq * 4];
        }
        #pragma unroll
        for (int kk = 0; kk < 2; ++kk) {
            const int kb = kk * 32 + (lane >> 4) * 8;
            s8v a[2], bb[2];
            #pragma unroll
            for (int i = 0; i < 2; ++i)
                a[i] = *(const s8v*)&Aal[swi(wm * 32 + i * 16 + (lane & 15), kb)];
            #pragma unroll
            for (int j = 0; j < 2; ++j)
                bb[j] = *(const s8v*)&Xs[swi(wn * 32 + j * 16 + (lane & 15), kb)];
            #pragma unroll
            for (int i = 0; i < 2; ++i)
                #pragma unroll
                for (int j = 0; j < 2; ++j)
                    acc[i][j] = MF(a[i], bb[j], acc[i][j]);
        }
        if (t < 15) cur = nxt;
    }
    __syncthreads();
    #pragma unroll
    for (int i = 0; i < 2; ++i)
        #pragma unroll
        for (int j = 0; j < 2; ++j)
            #pragma unroll
            for (int rr = 0; rr < 4; ++rr)
                ts[wm * 32 + i * 16 + (lane >> 4) * 4 + rr][wn * 32 + j * 16 + (lane & 15)] = acc[i][j][rr];
    __syncthreads();
    const int o = tid >> 2, dofs = (tid & 3) * 16;
    float* op = outP + ((size_t)b * OSo + o) * Dd + d0 + dofs;
    #pragma unroll
    for (int w = 0; w < 4; ++w)
        *(float4*)&op[w * 4] = *(float4*)&ts[o][dofs + w * 4];
}

// ---------------------------------------------------------------------------
// k4: Xh = bf16(relu(BN((XpP0+XpP1)@h_w + h_b)))  tile 64x64, dbuf+prefetch
// (round-10 exact)
// ---------------------------------------------------------------------------
struct R4 { float4 p[8]; s8v w[2]; };

__global__ __launch_bounds__(256) void k4(const float* __restrict__ XpP,
                                          const short* __restrict__ h_wT,
                                          const float* __restrict__ h_b,
                                          const float* __restrict__ gamma,
                                          const float* __restrict__ beta,
                                          const float* __restrict__ mean,
                                          const float* __restrict__ var,
                                          short* __restrict__ Xh) {
    __shared__ __align__(16) char smem[32768];
    short* tsb = (short*)smem;                              // epilogue alias [64][64]
    const int tid = threadIdx.x, lane = tid & 63, wave = tid >> 6;
    const int wm = wave >> 1, wn = wave & 1;
    const int h0 = blockIdx.x * 64, m0 = blockIdx.y * 64;
    const int r = tid >> 2, kofs = (tid & 3) * 16;
    const size_t ZS = (size_t)Bb * OSo * Dd;
    f32x4 acc[2][2] = {};
    R4 cur, nxt;
    #pragma unroll
    for (int w = 0; w < 2; ++w) {
        const float* p0 = XpP + (size_t)(m0 + r) * Dd + kofs + w * 8;
        cur.p[w*4+0] = *(const float4*)&p0[0];
        cur.p[w*4+1] = *(const float4*)&p0[4];
        cur.p[w*4+2] = *(const float4*)&p0[ZS];
        cur.p[w*4+3] = *(const float4*)&p0[ZS + 4];
        cur.w[w]     = *(const s8v*)&h_wT[(size_t)(h0 + r) * Dd + kofs + w * 8];
    }
    #pragma unroll
    for (int t = 0; t < 16; ++t) {
        short* As = (short*)(smem + (t & 1) * 8192);
        short* Bs = (short*)(smem + 16384 + (t & 1) * 8192);
        #pragma unroll
        for (int w = 0; w < 2; ++w) {
            const float* f0 = (const float*)&cur.p[w*4];
            const float* f1 = (const float*)&cur.p[w*4+2];
            s8v s;
            #pragma unroll
            for (int e = 0; e < 8; ++e) s[e] = f2b(f0[e] + f1[e]);
            *(s8v*)&As[swi(r, kofs + w * 8)] = s;
            *(s8v*)&Bs[swi(r, kofs + w * 8)] = cur.w[w];
        }
        fastbar();
        if (t < 15) {
            const int k0 = (t + 1) * 64;
            #pragma unroll
            for (int w = 0; w < 2; ++w) {
                const float* p0 = XpP + (size_t)(m0 + r) * Dd + k0 + kofs + w * 8;
                nxt.p[w*4+0] = *(const float4*)&p0[0];
                nxt.p[w*4+1] = *(const float4*)&p0[4];
                nxt.p[w*4+2] = *(const float4*)&p0[ZS];
                nxt.p[w*4+3] = *(const float4*)&p0[ZS + 4];
                nxt.w[w]     = *(const s8v*)&h_wT[(size_t)(h0 + r) * Dd + k0 + kofs + w * 8];
            }
        }
        #pragma unroll
        for (int kk = 0; kk < 2; ++kk) {
            const int kb = kk * 32 + (lane >> 4) * 8;
            s8v a[2], bb[2];
            #pragma unroll
            for (int i = 0; i < 2; ++i)
                a[i] = *(const s8v*)&As[swi(wm * 32 + i * 16 + (lane & 15), kb)];
            #pragma unroll
            for (int j = 0; j < 2; ++j)
                bb[j] = *(const s8v*)&Bs[swi(wn * 32 + j * 16 + (lane & 15), kb)];
            #pragma unroll
            for (int i = 0; i < 2; ++i)
                #pragma unroll
                for (int j = 0; j < 2; ++j)
                    acc[i][j] = MF(a[i], bb[j], acc[i][j]);
        }
        if (t < 15) cur = nxt;
    }
    __syncthreads();
    #pragma unroll
    for (int j = 0; j < 2; ++j) {
        const int h = h0 + wn * 32 + j * 16 + (lane & 15);
        const float sc = gamma[h] * rsqrtf(var[h] + BN_EPS);
        const float of = (h_b[h] - mean[h]) * sc + beta[h];
        #pragma unroll
        for (int i = 0; i < 2; ++i)
            #pragma unroll
            for (int rr = 0; rr < 4; ++rr) {
                const int ml = wm * 32 + i * 16 + (lane >> 4) * 4 + rr;
                tsb[ml * 64 + wn * 32 + j * 16 + (lane & 15)] = f2b(fmaxf(0.f, acc[i][j][rr] * sc + of));
            }
    }
    __syncthreads();
    #pragma unroll
    for (int w = 0; w < 2; ++w)
        *(s8v*)&Xh[(size_t)(m0 + r) * LABh + h0 + kofs + w * 8] = *(const s8v*)&tsb[r * 64 + kofs + w * 8];
}

// ---------------------------------------------------------------------------
// k56: fused scores+softmax+weighted-sum.  One block = (b, 16 candidates).
// Phase 1: sc[16][64] = bf16(labD[cand]) @ Xh[b]^T  (MFMA, K=1024, dbuf+fastbar)
// Phase 2: softmax rows over o=64 (in LDS), out = alpha2 @ Xh (f32 VALU).
// 256 blocks, XCD-grouped by b.
// ---------------------------------------------------------------------------
struct R56 { float4 ld; s8v xh[2]; };

__global__ __launch_bounds__(256) void k56(const int* __restrict__ cand,
                                           const float* __restrict__ labD,
                                           const short* __restrict__ Xh,
                                           float* __restrict__ out) {
    __shared__ __align__(16) char smem[20608];
    float (*ts)[68] = (float(*)[68])smem;                   // 4352B, alias after loop
    float (*al)[64] = (float(*)[64])(smem + 4608);          // 4096B
    int* cidx = (int*)(smem + 20480);                       // 64B
    const int tid = threadIdx.x, lane = tid & 63, wave = tid >> 6;
    const int id = blockIdx.x;
    const int slot = id >> 3;
    const int b = (id & 7) * 2 + (slot >> 4);               // XCD-grouped by b
    const int c0 = (slot & 15) * 16;
    if (tid < 16) cidx[tid] = cand[b * NCc + c0 + tid];
    __syncthreads();
    const int ar = tid >> 4, ak = (tid & 15) * 4;           // A staging: 16 rows x 64 k
    const int br = tid >> 2, bk = (tid & 3) * 16;           // B staging: 64 rows x 64 k
    const float* lrow = labD + (size_t)cidx[ar] * LABh;
    const short* xb = Xh + (size_t)b * OSo * LABh;
    f32x4 acc = {};
    R56 cur, nxt;
    cur.ld    = *(const float4*)&lrow[ak];
    cur.xh[0] = *(const s8v*)&xb[(size_t)br * LABh + bk];
    cur.xh[1] = *(const s8v*)&xb[(size_t)br * LABh + bk + 8];
    #pragma unroll
    for (int t = 0; t < 16; ++t) {
        short* As = (short*)(smem + (t & 1) * 10240);       // 2KB
        short* Bs = As + 1024;                              // 8KB
        {
            s4v sa;
            sa[0] = f2b(cur.ld.x); sa[1] = f2b(cur.ld.y);
            sa[2] = f2b(cur.ld.z); sa[3] = f2b(cur.ld.w);
            *(s4v*)&As[swi(ar, ak)] = sa;
            *(s8v*)&Bs[swi(br, bk)]     = cur.xh[0];
            *(s8v*)&Bs[swi(br, bk + 8)] = cur.xh[1];
        }
        fastbar();
        if (t < 15) {
            const int k0 = (t + 1) * 64;
            nxt.ld    = *(const float4*)&lrow[k0 + ak];
            nxt.xh[0] = *(const s8v*)&xb[(size_t)br * LABh + k0 + bk];
            nxt.xh[1] = *(const s8v*)&xb[(size_t)br * LABh + k0 + bk + 8];
        }
        #pragma unroll
        for (int kk = 0; kk < 2; ++kk) {
            const int kb = kk * 32 + (lane >> 4) * 8;
            s8v a  = *(const s8v*)&As[swi(lane & 15, kb)];
            s8v bv = *(const s8v*)&Bs[swi(wave * 16 + (lane & 15), kb)];
            acc = MF(a, bv, acc);
        }
        if (t < 15) cur = nxt;
    }
    __syncthreads();                                        // staging done everywhere
    #pragma unroll
    for (int rr = 0; rr < 4; ++rr)
        ts[(lane >> 4) * 4 + rr][wave * 16 + (lane & 15)] = acc[rr];
    __syncthreads();
    // softmax over o per candidate row (16 rows x 16 threads each)
    {
        const int cl = tid >> 4, t16 = tid & 15;
        float v[4];
        float m = -1e30f;
        #pragma unroll
        for (int j = 0; j < 4; ++j) { v[j] = ts[cl][t16 + j * 16]; m = fmaxf(m, v[j]); }
        #pragma unroll
        for (int off = 8; off; off >>= 1) m = fmaxf(m, __shfl_xor(m, off, 16));
        float s = 0.f;
        #pragma unroll
        for (int j = 0; j < 4; ++j) { v[j] = __expf(v[j] - m); s += v[j]; }
        #pragma unroll
        for (int off = 8; off; off >>= 1) s += __shfl_xor(s, off, 16);
        const float inv = 1.f / s;
        #pragma unroll
        for (int j = 0; j < 4; ++j) al[cl][t16 + j * 16] = v[j] * inv;
    }
    __syncthreads();
    // phase 2: out[c][h] = sum_o al[c][o] * Xh[b][o][h]   (f32, as old k6)
    const int h0 = tid * 4;
    float acc2[16][4] = {};
    for (int o = 0; o < OSo; ++o) {
        s4v xv = *(const s4v*)&xb[(size_t)o * LABh + h0];
        const float x0 = b2f(xv[0]), x1 = b2f(xv[1]), x2 = b2f(xv[2]), x3 = b2f(xv[3]);
        #pragma unroll
        for (int c = 0; c < 16; ++c) {
            const float w = al[c][o];
            acc2[c][0] += w * x0; acc2[c][1] += w * x1;
            acc2[c][2] += w * x2; acc2[c][3] += w * x3;
        }
    }
    #pragma unroll
    for (int c = 0; c < 16; ++c) {
        float4 v; v.x = acc2[c][0]; v.y = acc2[c][1]; v.z = acc2[c][2]; v.w = acc2[c][3];
        *(float4*)&out[((size_t)b * NCc + c0 + c) * LABh + h0] = v;
    }
}

// ---------------------------------------------------------------------------
extern "C" void kernel_launch(void* const* d_in, const int* in_sizes, int n_in,
                              void* d_out, int out_size, void* d_ws, size_t ws_size,
                              hipStream_t stream) {
    (void)in_sizes; (void)n_in; (void)out_size; (void)ws_size;
    const float* X      = (const float*)d_in[0];
    const int*   cand   = (const int*)  d_in[1];
    const float* a_w    = (const float*)d_in[2];
    const float* a_b    = (const float*)d_in[3];
    const float* h_w    = (const float*)d_in[4];
    const float* h_b    = (const float*)d_in[5];
    const float* gamma  = (const float*)d_in[6];
    const float* beta   = (const float*)d_in[7];
    const float* mean   = (const float*)d_in[8];
    const float* var    = (const float*)d_in[9];
    const float* labDesc= (const float*)d_in[10];
    float* outp = (float*)d_out;

    char* ws = (char*)d_ws;
    float* StP  = (float*)ws;                               // 16MB (2 partials); XpP aliases after k2
    float* XpP  = (float*)ws;                               // 8MB (2 partials)
    short* aBf  = (short*)(ws + ((size_t)16 << 20));        // 4MB alpha bf16
    short* Xh   = (short*)(ws + ((size_t)20 << 20));        // 2MB
    short* a_wT = (short*)(ws + ((size_t)26 << 20));        // 128KB
    short* h_wT = (short*)(ws + ((size_t)27 << 20));        // 2MB

    k0 <<<272,              256, 0, stream>>>(h_w, a_w, h_wT, a_wT);
    k1 <<<dim3(32, 16, 2),  256, 0, stream>>>(X, a_wT, StP);
    k2 <<<Bb * OSo,         256, 0, stream>>>(StP, a_b, aBf);
    k3 <<<512,              256, 0, stream>>>(X, aBf, XpP);
    k4 <<<dim3(16, 16),     256, 0, stream>>>(XpP, h_wT, h_b, gamma, beta, mean, var, Xh);
    k56<<<256,              256, 0, stream>>>(cand, labDesc, Xh, outp);
}

// Round 12
// 99.510 us; speedup vs baseline: 1.6083x; 1.0668x over previous
//
#include <hip/hip_runtime.h>
#include <hip/hip_bf16.h>
#include <math.h>

#define Bb   16
#define Ll   2048
#define Dd   1024
#define OSo  64
#define NCc  256
#define LABh 1024
#define BN_EPS 1e-5f

typedef short s8v  __attribute__((ext_vector_type(8)));   // 8 bf16 = 4 VGPR
typedef short s4v  __attribute__((ext_vector_type(4)));
typedef float f32x4 __attribute__((ext_vector_type(4)));

__device__ __forceinline__ short f2b(float f) {
    __hip_bfloat16 h = __float2bfloat16(f);
    short s;
    __builtin_memcpy(&s, &h, 2);
    return s;
}
__device__ __forceinline__ float b2f(short s) {
    union { unsigned u; float f; } v; v.u = ((unsigned)(unsigned short)s) << 16;
    return v.f;
}
// async global->LDS DMA, 16B per lane (dest = wave-uniform base + lane*16)
__device__ __forceinline__ void g2lds16(const void* g, void* l) {
    __builtin_amdgcn_global_load_lds(
        (const __attribute__((address_space(1))) void*)g,
        (__attribute__((address_space(3))) void*)l, 16, 0, 0);
}
// Barrier without vmcnt(0) drain: waits only this wave's LDS ops.
__device__ __forceinline__ void fastbar() {
    asm volatile("s_waitcnt lgkmcnt(0)\n\ts_barrier" ::: "memory");
}
// swizzled short-index into a [rows][64] bf16 LDS tile (row stride 128B).
__device__ __forceinline__ int swi(int row, int kElem) {
    return (row * 128 + ((kElem * 2) ^ ((row & 7) << 4))) >> 1;
}
__device__ __forceinline__ f32x4 MF(s8v a, s8v b, f32x4 c) {
    return __builtin_amdgcn_mfma_f32_16x16x32_bf16(a, b, c, 0, 0, 0);
}

// ---------------------------------------------------------------------------
// k0: transpose+convert weights.
// ---------------------------------------------------------------------------
__global__ __launch_bounds__(256) void k0(const float* __restrict__ h_w,
                                          const float* __restrict__ a_w,
                                          short* __restrict__ h_wT,
                                          short* __restrict__ a_wT) {
    __shared__ float t[64][68];
    const int tid = threadIdx.x, id = blockIdx.x;
    const float* src; short* dst; int srw, d0, y0;
    if (id < 256) { src = h_w; dst = h_wT; srw = LABh; d0 = (id & 15) * 64; y0 = (id >> 4) * 64; }
    else          { src = a_w; dst = a_wT; srw = OSo;  d0 = (id - 256) * 64; y0 = 0; }
    const int r = tid >> 2, cofs = (tid & 3) * 16;
    #pragma unroll
    for (int w = 0; w < 4; ++w) {
        float4 v = *(const float4*)&src[(size_t)(d0 + r) * srw + y0 + cofs + w * 4];
        t[r][cofs + w * 4 + 0] = v.x;
        t[r][cofs + w * 4 + 1] = v.y;
        t[r][cofs + w * 4 + 2] = v.z;
        t[r][cofs + w * 4 + 3] = v.w;
    }
    __syncthreads();
    s8v o0, o1;
    #pragma unroll
    for (int e = 0; e < 8; ++e) { o0[e] = f2b(t[cofs + e][r]); o1[e] = f2b(t[cofs + 8 + e][r]); }
    *(s8v*)&dst[(size_t)(y0 + r) * Dd + d0 + cofs]     = o0;
    *(s8v*)&dst[(size_t)(y0 + r) * Dd + d0 + cofs + 8] = o1;
}

// ---------------------------------------------------------------------------
// k1: St[b][o][l] = X@a_w (bias in k2).  tile 64(l)x64(o), K=1024.
// DMA staging via global_load_lds width-16 (m97 pattern): LDS linear dest,
// XOR-swizzled global SOURCE + same XOR on the LDS read (rule 21).
// A tile staged as f32 (16KB x2), converted to bf16 at read time.
// ---------------------------------------------------------------------------
__global__ __launch_bounds__(256) void k1(const float* __restrict__ X,
                                          const short* __restrict__ a_wT,
                                          float* __restrict__ St) {
    __shared__ __align__(16) char smem[49152];   // A dbuf 2x16KB @0; B dbuf 2x8KB @32768
    float (*ts)[65] = (float(*)[65])smem;        // epilogue alias
    const int tid = threadIdx.x, lane = tid & 63, wave = tid >> 6;
    const int wm = wave >> 1, wn = wave & 1;
    const int b = blockIdx.y, l0 = blockIdx.x * 64;
    const float* Xb = X + ((size_t)b * Ll + l0) * Dd;
    const int akb = (lane & 15) * 16;            // byte-in-row for A staging
    const int bkb = (lane & 7) * 16;             // byte-in-row for B staging
    f32x4 acc[2][2] = {};

    auto issue = [&](int t, int k0) {
        char* Ab = smem + (t & 1) * 16384;
        #pragma unroll
        for (int q = 0; q < 4; ++q) {
            const int chunk = wave * 4 + q;                     // 1KB chunk, 4 rows
            const int row = chunk * 4 + (lane >> 4);
            const char* g = (const char*)Xb + (size_t)row * 4096 + k0 * 4
                          + (akb ^ ((row & 7) << 4));
            g2lds16(g, Ab + chunk * 1024);
        }
        char* Bbuf = smem + 32768 + (t & 1) * 8192;
        #pragma unroll
        for (int q = 0; q < 2; ++q) {
            const int chunk = wave * 2 + q;                     // 1KB chunk, 8 rows
            const int row = chunk * 8 + (lane >> 3);
            const char* g = (const char*)a_wT + (size_t)row * 2048 + k0 * 2
                          + (bkb ^ ((row & 7) << 4));
            g2lds16(g, Bbuf + chunk * 1024);
        }
    };

    issue(0, 0);
    #pragma unroll
    for (int t = 0; t < 16; ++t) {
        if (t < 15) issue(t + 1, (t + 1) * 64);
        __syncthreads();                          // drains DMA -> buf[t&1] ready
        const char* Ab = smem + (t & 1) * 16384;
        const char* Bbuf = smem + 32768 + (t & 1) * 8192;
        #pragma unroll
        for (int kk = 0; kk < 2; ++kk) {
            s8v a[2], bv[2];
            #pragma unroll
            for (int i = 0; i < 2; ++i) {
                const int row = wm * 32 + i * 16 + (lane & 15);
                const int sw = (row & 7) << 4;
                const int kbyte = kk * 128 + (lane >> 4) * 32;
                float4 v0 = *(const float4*)(Ab + row * 256 + ((kbyte) ^ sw));
                float4 v1 = *(const float4*)(Ab + row * 256 + ((kbyte + 16) ^ sw));
                s8v s;
                s[0]=f2b(v0.x); s[1]=f2b(v0.y); s[2]=f2b(v0.z); s[3]=f2b(v0.w);
                s[4]=f2b(v1.x); s[5]=f2b(v1.y); s[6]=f2b(v1.z); s[7]=f2b(v1.w);
                a[i] = s;
            }
            #pragma unroll
            for (int j = 0; j < 2; ++j) {
                const int row = wn * 32 + j * 16 + (lane & 15);
                const int sw = (row & 7) << 4;
                const int kbyte = kk * 64 + (lane >> 4) * 16;
                bv[j] = *(const s8v*)(Bbuf + row * 128 + (kbyte ^ sw));
            }
            #pragma unroll
            for (int i = 0; i < 2; ++i)
                #pragma unroll
                for (int j = 0; j < 2; ++j)
                    acc[i][j] = MF(a[i], bv[j], acc[i][j]);
        }
        __syncthreads();                          // all reads done before re-stage
    }
    #pragma unroll
    for (int i = 0; i < 2; ++i)
        #pragma unroll
        for (int j = 0; j < 2; ++j)
            #pragma unroll
            for (int rr = 0; rr < 4; ++rr)
                ts[wm * 32 + i * 16 + (lane >> 4) * 4 + rr][wn * 32 + j * 16 + (lane & 15)] = acc[i][j][rr];
    __syncthreads();
    const int o = tid >> 2, lofs = (tid & 3) * 16;
    float* Sp = St + ((size_t)b * OSo + o) * Ll + l0 + lofs;
    #pragma unroll
    for (int w = 0; w < 4; ++w) {
        float4 v;
        v.x = ts[lofs + w * 4 + 0][o];
        v.y = ts[lofs + w * 4 + 1][o];
        v.z = ts[lofs + w * 4 + 2][o];
        v.w = ts[lofs + w * 4 + 3][o];
        *(float4*)&Sp[w * 4] = v;
    }
}

// ---------------------------------------------------------------------------
// k2: St + a_b, softmax over L, write alpha bf16.  float4-vectorized.
// ---------------------------------------------------------------------------
__global__ __launch_bounds__(256) void k2(const float* __restrict__ St,
                                          const float* __restrict__ a_b,
                                          short* __restrict__ aBf) {
    __shared__ float row[Ll];
    __shared__ float red[8];
    const float* p0 = St + (size_t)blockIdx.x * Ll;
    short* ab = aBf + (size_t)blockIdx.x * Ll;
    const int tid = threadIdx.x;
    const int wave = tid >> 6, lane = tid & 63;
    const float bias = a_b[blockIdx.x & (OSo - 1)];
    const int base = tid * 4;
    float m = -1e30f;
    #pragma unroll
    for (int i = base; i < Ll; i += 1024) {
        float4 a = *(const float4*)&p0[i];
        float4 v;
        v.x = a.x + bias; v.y = a.y + bias;
        v.z = a.z + bias; v.w = a.w + bias;
        *(float4*)&row[i] = v;
        m = fmaxf(m, fmaxf(fmaxf(v.x, v.y), fmaxf(v.z, v.w)));
    }
    #pragma unroll
    for (int off = 32; off; off >>= 1) m = fmaxf(m, __shfl_down(m, off));
    if (lane == 0) red[wave] = m;
    __syncthreads();
    if (tid == 0) red[4] = fmaxf(fmaxf(red[0], red[1]), fmaxf(red[2], red[3]));
    __syncthreads();
    const float M = red[4];
    float s = 0.f;
    #pragma unroll
    for (int i = base; i < Ll; i += 1024) {
        float4 v = *(const float4*)&row[i];
        v.x = __expf(v.x - M); v.y = __expf(v.y - M);
        v.z = __expf(v.z - M); v.w = __expf(v.w - M);
        *(float4*)&row[i] = v;
        s += (v.x + v.y) + (v.z + v.w);
    }
    __syncthreads();
    #pragma unroll
    for (int off = 32; off; off >>= 1) s += __shfl_down(s, off);
    if (lane == 0) red[wave] = s;
    __syncthreads();
    if (tid == 0) red[4] = 1.f / (red[0] + red[1] + red[2] + red[3]);
    __syncthreads();
    const float inv = red[4];
    #pragma unroll
    for (int i = base; i < Ll; i += 1024) {
        float4 v = *(const float4*)&row[i];
        s4v o;
        o[0] = f2b(v.x * inv); o[1] = f2b(v.y * inv);
        o[2] = f2b(v.z * inv); o[3] = f2b(v.w * inv);
        *(s4v*)&ab[i] = o;
    }
}

// ---------------------------------------------------------------------------
// k3: Xp_part[z] = alpha_half @ X_half.  tile 64(o)x64(d), split-K=2,
// dbuf+prefetch+fastbar.  512 blocks, XCD-grouped by b.  (round-11 exact)
// ---------------------------------------------------------------------------
struct R3 { s8v al[2]; float4 xv[4]; };

__global__ __launch_bounds__(256) void k3(const float* __restrict__ X,
                                          const short* __restrict__ aBf,
                                          float* __restrict__ XpP) {
    __shared__ __align__(16) char smem[32768];
    float (*ts)[68] = (float(*)[68])smem;                   // epilogue alias
    const int tid = threadIdx.x;
    const int lane = tid & 63, wave = tid >> 6;
    const int wm = wave >> 1, wn = wave & 1;
    const int id = blockIdx.x;
    const int slot = id >> 3;
    const int b = (id & 7) * 2 + (slot >> 5);
    const int inner = slot & 31;
    const int dt = inner & 15, z = inner >> 4;
    const int d0 = dt * 64;
    const float* Xb = X + (size_t)b * Ll * Dd;
    const short* ab = aBf + (size_t)b * OSo * Ll;
    float* outP = XpP + (size_t)z * ((size_t)Bb * OSo * Dd);
    f32x4 acc[2][2] = {};
    const int arow = tid >> 2, akofs = (tid & 3) * 16;
    const int lq = tid & 15, dq = tid >> 4;
    const int lbase = z * 1024;
    R3 cur, nxt;
    #pragma unroll
    for (int w = 0; w < 2; ++w)
        cur.al[w] = *(const s8v*)&ab[(size_t)arow * Ll + lbase + akofs + w * 8];
    #pragma unroll
    for (int i = 0; i < 4; ++i)
        cur.xv[i] = *(const float4*)&Xb[(size_t)(lbase + lq * 4 + i) * Dd + d0 + dq * 4];
    #pragma unroll
    for (int t = 0; t < 16; ++t) {
        short* Aal = (short*)(smem + (t & 1) * 8192);
        short* Xs  = (short*)(smem + 16384 + (t & 1) * 8192);
        #pragma unroll
        for (int w = 0; w < 2; ++w)
            *(s8v*)&Aal[swi(arow, akofs + w * 8)] = cur.al[w];
        {
            const float* f = (const float*)cur.xv;          // f[i*4+j] = X[l=lq*4+i][d=dq*4+j]
            #pragma unroll
            for (int j = 0; j < 4; ++j) {
                const int rowd = dq * 4 + j;
                s4v sj;
                sj[0] = f2b(f[0 * 4 + j]);
                sj[1] = f2b(f[1 * 4 + j]);
                sj[2] = f2b(f[2 * 4 + j]);
                sj[3] = f2b(f[3 * 4 + j]);
                *(s4v*)&Xs[swi(rowd, lq * 4)] = sj;
            }
        }
        fastbar();
        if (t < 15) {
            const int l0 = lbase + (t + 1) * 64;
            #pragma unroll
            for (int w = 0; w < 2; ++w)
                nxt.al[w] = *(const s8v*)&ab[(size_t)arow * Ll + l0 + akofs + w * 8];
            #pragma unroll
            for (int i = 0; i < 4; ++i)
                nxt.xv[i] = *(const float4*)&Xb[(size_t)(l0 + lq * 4 + i) * Dd + d0 + dq * 4];
        }
        #pragma unroll
        for (int kk = 0; kk < 2; ++kk) {
            const int kb = kk * 32 + (lane >> 4) * 8;
            s8v a[2], bb[2];
            #pragma unroll
            for (int i = 0; i < 2; ++i)
                a[i] = *(const s8v*)&Aal[swi(wm * 32 + i * 16 + (lane & 15), kb)];
            #pragma unroll
            for (int j = 0; j < 2; ++j)
                bb[j] = *(const s8v*)&Xs[swi(wn * 32 + j * 16 + (lane & 15), kb)];
            #pragma unroll
            for (int i = 0; i < 2; ++i)
                #pragma unroll
                for (int j = 0; j < 2; ++j)
                    acc[i][j] = MF(a[i], bb[j], acc[i][j]);
        }
        if (t < 15) cur = nxt;
    }
    __syncthreads();
    #pragma unroll
    for (int i = 0; i < 2; ++i)
        #pragma unroll
        for (int j = 0; j < 2; ++j)
            #pragma unroll
            for (int rr = 0; rr < 4; ++rr)
                ts[wm * 32 + i * 16 + (lane >> 4) * 4 + rr][wn * 32 + j * 16 + (lane & 15)] = acc[i][j][rr];
    __syncthreads();
    const int o = tid >> 2, dofs = (tid & 3) * 16;
    float* op = outP + ((size_t)b * OSo + o) * Dd + d0 + dofs;
    #pragma unroll
    for (int w = 0; w < 4; ++w)
        *(float4*)&op[w * 4] = *(float4*)&ts[o][dofs + w * 4];
}

// ---------------------------------------------------------------------------
// k4: Xh = bf16(relu(BN((XpP0+XpP1)@h_w + h_b)))  tile 64x64, dbuf+prefetch.
// 1-D grid 256, XCD-grouped by m-tile (same-m h-tiles share an XCD's L2).
// ---------------------------------------------------------------------------
struct R4 { float4 p[8]; s8v w[2]; };

__global__ __launch_bounds__(256) void k4(const float* __restrict__ XpP,
                                          const short* __restrict__ h_wT,
                                          const float* __restrict__ h_b,
                                          const float* __restrict__ gamma,
                                          const float* __restrict__ beta,
                                          const float* __restrict__ mean,
                                          const float* __restrict__ var,
                                          short* __restrict__ Xh) {
    __shared__ __align__(16) char smem[32768];
    short* tsb = (short*)smem;                              // epilogue alias [64][64]
    const int tid = threadIdx.x, lane = tid & 63, wave = tid >> 6;
    const int wm = wave >> 1, wn = wave & 1;
    const int id = blockIdx.x;
    const int slot = id >> 3;
    const int mt = (id & 7) * 2 + (slot >> 4);              // same mt -> same XCD
    const int ht = slot & 15;
    const int h0 = ht * 64, m0 = mt * 64;
    const int r = tid >> 2, kofs = (tid & 3) * 16;
    const size_t ZS = (size_t)Bb * OSo * Dd;
    f32x4 acc[2][2] = {};
    R4 cur, nxt;
    #pragma unroll
    for (int w = 0; w < 2; ++w) {
        const float* p0 = XpP + (size_t)(m0 + r) * Dd + kofs + w * 8;
        cur.p[w*4+0] = *(const float4*)&p0[0];
        cur.p[w*4+1] = *(const float4*)&p0[4];
        cur.p[w*4+2] = *(const float4*)&p0[ZS];
        cur.p[w*4+3] = *(const float4*)&p0[ZS + 4];
        cur.w[w]     = *(const s8v*)&h_wT[(size_t)(h0 + r) * Dd + kofs + w * 8];
    }
    #pragma unroll
    for (int t = 0; t < 16; ++t) {
        short* As = (short*)(smem + (t & 1) * 8192);
        short* Bs = (short*)(smem + 16384 + (t & 1) * 8192);
        #pragma unroll
        for (int w = 0; w < 2; ++w) {
            const float* f0 = (const float*)&cur.p[w*4];
            const float* f1 = (const float*)&cur.p[w*4+2];
            s8v s;
            #pragma unroll
            for (int e = 0; e < 8; ++e) s[e] = f2b(f0[e] + f1[e]);
            *(s8v*)&As[swi(r, kofs + w * 8)] = s;
            *(s8v*)&Bs[swi(r, kofs + w * 8)] = cur.w[w];
        }
        fastbar();
        if (t < 15) {
            const int k0 = (t + 1) * 64;
            #pragma unroll
            for (int w = 0; w < 2; ++w) {
                const float* p0 = XpP + (size_t)(m0 + r) * Dd + k0 + kofs + w * 8;
                nxt.p[w*4+0] = *(const float4*)&p0[0];
                nxt.p[w*4+1] = *(const float4*)&p0[4];
                nxt.p[w*4+2] = *(const float4*)&p0[ZS];
                nxt.p[w*4+3] = *(const float4*)&p0[ZS + 4];
                nxt.w[w]     = *(const s8v*)&h_wT[(size_t)(h0 + r) * Dd + k0 + kofs + w * 8];
            }
        }
        #pragma unroll
        for (int kk = 0; kk < 2; ++kk) {
            const int kb = kk * 32 + (lane >> 4) * 8;
            s8v a[2], bb[2];
            #pragma unroll
            for (int i = 0; i < 2; ++i)
                a[i] = *(const s8v*)&As[swi(wm * 32 + i * 16 + (lane & 15), kb)];
            #pragma unroll
            for (int j = 0; j < 2; ++j)
                bb[j] = *(const s8v*)&Bs[swi(wn * 32 + j * 16 + (lane & 15), kb)];
            #pragma unroll
            for (int i = 0; i < 2; ++i)
                #pragma unroll
                for (int j = 0; j < 2; ++j)
                    acc[i][j] = MF(a[i], bb[j], acc[i][j]);
        }
        if (t < 15) cur = nxt;
    }
    __syncthreads();
    #pragma unroll
    for (int j = 0; j < 2; ++j) {
        const int h = h0 + wn * 32 + j * 16 + (lane & 15);
        const float sc = gamma[h] * rsqrtf(var[h] + BN_EPS);
        const float of = (h_b[h] - mean[h]) * sc + beta[h];
        #pragma unroll
        for (int i = 0; i < 2; ++i)
            #pragma unroll
            for (int rr = 0; rr < 4; ++rr) {
                const int ml = wm * 32 + i * 16 + (lane >> 4) * 4 + rr;
                tsb[ml * 64 + wn * 32 + j * 16 + (lane & 15)] = f2b(fmaxf(0.f, acc[i][j][rr] * sc + of));
            }
    }
    __syncthreads();
    #pragma unroll
    for (int w = 0; w < 2; ++w)
        *(s8v*)&Xh[(size_t)(m0 + r) * LABh + h0 + kofs + w * 8] = *(const s8v*)&tsb[r * 64 + kofs + w * 8];
}

// ---------------------------------------------------------------------------
// k56: fused scores+softmax+weighted-sum.  (round-11 exact)
// ---------------------------------------------------------------------------
struct R56 { float4 ld; s8v xh[2]; };

__global__ __launch_bounds__(256) void k56(const int* __restrict__ cand,
                                           const float* __restrict__ labD,
                                           const short* __restrict__ Xh,
                                           float* __restrict__ out) {
    __shared__ __align__(16) char smem[20608];
    float (*ts)[68] = (float(*)[68])smem;                   // alias after loop
    float (*al)[64] = (float(*)[64])(smem + 4608);
    int* cidx = (int*)(smem + 20480);
    const int tid = threadIdx.x, lane = tid & 63, wave = tid >> 6;
    const int id = blockIdx.x;
    const int slot = id >> 3;
    const int b = (id & 7) * 2 + (slot >> 4);               // XCD-grouped by b
    const int c0 = (slot & 15) * 16;
    if (tid < 16) cidx[tid] = cand[b * NCc + c0 + tid];
    __syncthreads();
    const int ar = tid >> 4, ak = (tid & 15) * 4;
    const int br = tid >> 2, bk = (tid & 3) * 16;
    const float* lrow = labD + (size_t)cidx[ar] * LABh;
    const short* xb = Xh + (size_t)b * OSo * LABh;
    f32x4 acc = {};
    R56 cur, nxt;
    cur.ld    = *(const float4*)&lrow[ak];
    cur.xh[0] = *(const s8v*)&xb[(size_t)br * LABh + bk];
    cur.xh[1] = *(const s8v*)&xb[(size_t)br * LABh + bk + 8];
    #pragma unroll
    for (int t = 0; t < 16; ++t) {
        short* As = (short*)(smem + (t & 1) * 10240);
        short* Bs = As + 1024;
        {
            s4v sa;
            sa[0] = f2b(cur.ld.x); sa[1] = f2b(cur.ld.y);
            sa[2] = f2b(cur.ld.z); sa[3] = f2b(cur.ld.w);
            *(s4v*)&As[swi(ar, ak)] = sa;
            *(s8v*)&Bs[swi(br, bk)]     = cur.xh[0];
            *(s8v*)&Bs[swi(br, bk + 8)] = cur.xh[1];
        }
        fastbar();
        if (t < 15) {
            const int k0 = (t + 1) * 64;
            nxt.ld    = *(const float4*)&lrow[k0 + ak];
            nxt.xh[0] = *(const s8v*)&xb[(size_t)br * LABh + k0 + bk];
            nxt.xh[1] = *(const s8v*)&xb[(size_t)br * LABh + k0 + bk + 8];
        }
        #pragma unroll
        for (int kk = 0; kk < 2; ++kk) {
            const int kb = kk * 32 + (lane >> 4) * 8;
            s8v a  = *(const s8v*)&As[swi(lane & 15, kb)];
            s8v bv = *(const s8v*)&Bs[swi(wave * 16 + (lane & 15), kb)];
            acc = MF(a, bv, acc);
        }
        if (t < 15) cur = nxt;
    }
    __syncthreads();
    #pragma unroll
    for (int rr = 0; rr < 4; ++rr)
        ts[(lane >> 4) * 4 + rr][wave * 16 + (lane & 15)] = acc[rr];
    __syncthreads();
    {
        const int cl = tid >> 4, t16 = tid & 15;
        float v[4];
        float m = -1e30f;
        #pragma unroll
        for (int j = 0; j < 4; ++j) { v[j] = ts[cl][t16 + j * 16]; m = fmaxf(m, v[j]); }
        #pragma unroll
        for (int off = 8; off; off >>= 1) m = fmaxf(m, __shfl_xor(m, off, 16));
        float s = 0.f;
        #pragma unroll
        for (int j = 0; j < 4; ++j) { v[j] = __expf(v[j] - m); s += v[j]; }
        #pragma unroll
        for (int off = 8; off; off >>= 1) s += __shfl_xor(s, off, 16);
        const float inv = 1.f / s;
        #pragma unroll
        for (int j = 0; j < 4; ++j) al[cl][t16 + j * 16] = v[j] * inv;
    }
    __syncthreads();
    const int h0 = tid * 4;
    float acc2[16][4] = {};
    for (int o = 0; o < OSo; ++o) {
        s4v xv = *(const s4v*)&xb[(size_t)o * LABh + h0];
        const float x0 = b2f(xv[0]), x1 = b2f(xv[1]), x2 = b2f(xv[2]), x3 = b2f(xv[3]);
        #pragma unroll
        for (int c = 0; c < 16; ++c) {
            const float w = al[c][o];
            acc2[c][0] += w * x0; acc2[c][1] += w * x1;
            acc2[c][2] += w * x2; acc2[c][3] += w * x3;
        }
    }
    #pragma unroll
    for (int c = 0; c < 16; ++c) {
        float4 v; v.x = acc2[c][0]; v.y = acc2[c][1]; v.z = acc2[c][2]; v.w = acc2[c][3];
        *(float4*)&out[((size_t)b * NCc + c0 + c) * LABh + h0] = v;
    }
}

// ---------------------------------------------------------------------------
extern "C" void kernel_launch(void* const* d_in, const int* in_sizes, int n_in,
                              void* d_out, int out_size, void* d_ws, size_t ws_size,
                              hipStream_t stream) {
    (void)in_sizes; (void)n_in; (void)out_size; (void)ws_size;
    const float* X      = (const float*)d_in[0];
    const int*   cand   = (const int*)  d_in[1];
    const float* a_w    = (const float*)d_in[2];
    const float* a_b    = (const float*)d_in[3];
    const float* h_w    = (const float*)d_in[4];
    const float* h_b    = (const float*)d_in[5];
    const float* gamma  = (const float*)d_in[6];
    const float* beta   = (const float*)d_in[7];
    const float* mean   = (const float*)d_in[8];
    const float* var    = (const float*)d_in[9];
    const float* labDesc= (const float*)d_in[10];
    float* outp = (float*)d_out;

    char* ws = (char*)d_ws;
    float* St   = (float*)ws;                               // 4MB; XpP aliases after k2
    float* XpP  = (float*)ws;                               // 8MB (2 partials)
    short* aBf  = (short*)(ws + ((size_t)16 << 20));        // 4MB alpha bf16
    short* Xh   = (short*)(ws + ((size_t)20 << 20));        // 2MB
    short* a_wT = (short*)(ws + ((size_t)26 << 20));        // 128KB
    short* h_wT = (short*)(ws + ((size_t)27 << 20));        // 2MB

    k0 <<<272,          256, 0, stream>>>(h_w, a_w, h_wT, a_wT);
    k1 <<<dim3(32, 16), 256, 0, stream>>>(X, a_wT, St);
    k2 <<<Bb * OSo,     256, 0, stream>>>(St, a_b, aBf);
    k3 <<<512,          256, 0, stream>>>(X, aBf, XpP);
    k4 <<<256,          256, 0, stream>>>(XpP, h_wT, h_b, gamma, beta, mean, var, Xh);
    k56<<<256,          256, 0, stream>>>(cand, labDesc, Xh, outp);
}

// Round 13
// 94.391 us; speedup vs baseline: 1.6955x; 1.0542x over previous
//
#include <hip/hip_runtime.h>
#include <hip/hip_bf16.h>
#include <math.h>

#define Bb   16
#define Ll   2048
#define Dd   1024
#define OSo  64
#define NCc  256
#define LABh 1024
#define BN_EPS 1e-5f

typedef short s8v  __attribute__((ext_vector_type(8)));   // 8 bf16 = 4 VGPR
typedef short s4v  __attribute__((ext_vector_type(4)));
typedef float f32x4 __attribute__((ext_vector_type(4)));

__device__ __forceinline__ short f2b(float f) {
    __hip_bfloat16 h = __float2bfloat16(f);
    short s;
    __builtin_memcpy(&s, &h, 2);
    return s;
}
__device__ __forceinline__ float b2f(short s) {
    union { unsigned u; float f; } v; v.u = ((unsigned)(unsigned short)s) << 16;
    return v.f;
}
// async global->LDS DMA, 16B per lane (dest = wave-uniform base + lane*16)
__device__ __forceinline__ void g2lds16(const void* g, void* l) {
    __builtin_amdgcn_global_load_lds(
        (const __attribute__((address_space(1))) void*)g,
        (__attribute__((address_space(3))) void*)l, 16, 0, 0);
}
// Barrier without vmcnt(0) drain: waits only this wave's LDS ops.
__device__ __forceinline__ void fastbar() {
    asm volatile("s_waitcnt lgkmcnt(0)\n\ts_barrier" ::: "memory");
}
// Counted-vmcnt barriers for the DMA pipeline (T4): leave the newest 6
// in-flight loads (tile t+1) while guaranteeing tile t has landed.
__device__ __forceinline__ void dmabar6() {
    asm volatile("s_waitcnt vmcnt(6) lgkmcnt(0)\n\ts_barrier" ::: "memory");
}
__device__ __forceinline__ void dmabar0() {
    asm volatile("s_waitcnt vmcnt(0) lgkmcnt(0)\n\ts_barrier" ::: "memory");
}
// swizzled short-index into a [rows][64] bf16 LDS tile (row stride 128B).
__device__ __forceinline__ int swi(int row, int kElem) {
    return (row * 128 + ((kElem * 2) ^ ((row & 7) << 4))) >> 1;
}
__device__ __forceinline__ f32x4 MF(s8v a, s8v b, f32x4 c) {
    return __builtin_amdgcn_mfma_f32_16x16x32_bf16(a, b, c, 0, 0, 0);
}

// ---------------------------------------------------------------------------
// k0: transpose+convert weights.
// ---------------------------------------------------------------------------
__global__ __launch_bounds__(256) void k0(const float* __restrict__ h_w,
                                          const float* __restrict__ a_w,
                                          short* __restrict__ h_wT,
                                          short* __restrict__ a_wT) {
    __shared__ float t[64][68];
    const int tid = threadIdx.x, id = blockIdx.x;
    const float* src; short* dst; int srw, d0, y0;
    if (id < 256) { src = h_w; dst = h_wT; srw = LABh; d0 = (id & 15) * 64; y0 = (id >> 4) * 64; }
    else          { src = a_w; dst = a_wT; srw = OSo;  d0 = (id - 256) * 64; y0 = 0; }
    const int r = tid >> 2, cofs = (tid & 3) * 16;
    #pragma unroll
    for (int w = 0; w < 4; ++w) {
        float4 v = *(const float4*)&src[(size_t)(d0 + r) * srw + y0 + cofs + w * 4];
        t[r][cofs + w * 4 + 0] = v.x;
        t[r][cofs + w * 4 + 1] = v.y;
        t[r][cofs + w * 4 + 2] = v.z;
        t[r][cofs + w * 4 + 3] = v.w;
    }
    __syncthreads();
    s8v o0, o1;
    #pragma unroll
    for (int e = 0; e < 8; ++e) { o0[e] = f2b(t[cofs + e][r]); o1[e] = f2b(t[cofs + 8 + e][r]); }
    *(s8v*)&dst[(size_t)(y0 + r) * Dd + d0 + cofs]     = o0;
    *(s8v*)&dst[(size_t)(y0 + r) * Dd + d0 + cofs + 8] = o1;
}

// ---------------------------------------------------------------------------
// k1: St[b][o][l] = X@a_w (bias in k2).  tile 64(l)x64(o), K=1024.
// DMA staging (global_load_lds w16, rule-21 source/read XOR swizzle) +
// T4 counted-vmcnt barriers: tile t+1's 6 DMAs stay in flight across the
// barrier; only tile t's are drained.
// ---------------------------------------------------------------------------
__global__ __launch_bounds__(256) void k1(const float* __restrict__ X,
                                          const short* __restrict__ a_wT,
                                          float* __restrict__ St) {
    __shared__ __align__(16) char smem[49152];   // A dbuf 2x16KB @0; B dbuf 2x8KB @32768
    float (*ts)[65] = (float(*)[65])smem;        // epilogue alias
    const int tid = threadIdx.x, lane = tid & 63, wave = tid >> 6;
    const int wm = wave >> 1, wn = wave & 1;
    const int b = blockIdx.y, l0 = blockIdx.x * 64;
    const float* Xb = X + ((size_t)b * Ll + l0) * Dd;
    const int akb = (lane & 15) * 16;            // byte-in-row for A staging
    const int bkb = (lane & 7) * 16;             // byte-in-row for B staging
    f32x4 acc[2][2] = {};

    auto issue = [&](int t, int k0) {            // exactly 6 DMA ops per wave
        char* Ab = smem + (t & 1) * 16384;
        #pragma unroll
        for (int q = 0; q < 4; ++q) {
            const int chunk = wave * 4 + q;                     // 1KB chunk, 4 rows
            const int row = chunk * 4 + (lane >> 4);
            const char* g = (const char*)Xb + (size_t)row * 4096 + k0 * 4
                          + (akb ^ ((row & 7) << 4));
            g2lds16(g, Ab + chunk * 1024);
        }
        char* Bbuf = smem + 32768 + (t & 1) * 8192;
        #pragma unroll
        for (int q = 0; q < 2; ++q) {
            const int chunk = wave * 2 + q;                     // 1KB chunk, 8 rows
            const int row = chunk * 8 + (lane >> 3);
            const char* g = (const char*)a_wT + (size_t)row * 2048 + k0 * 2
                          + (bkb ^ ((row & 7) << 4));
            g2lds16(g, Bbuf + chunk * 1024);
        }
    };

    issue(0, 0);
    #pragma unroll
    for (int t = 0; t < 16; ++t) {
        if (t < 15) { issue(t + 1, (t + 1) * 64); dmabar6(); }
        else        { dmabar0(); }
        const char* Ab = smem + (t & 1) * 16384;
        const char* Bbuf = smem + 32768 + (t & 1) * 8192;
        #pragma unroll
        for (int kk = 0; kk < 2; ++kk) {
            s8v a[2], bv[2];
            #pragma unroll
            for (int i = 0; i < 2; ++i) {
                const int row = wm * 32 + i * 16 + (lane & 15);
                const int sw = (row & 7) << 4;
                const int kbyte = kk * 128 + (lane >> 4) * 32;
                float4 v0 = *(const float4*)(Ab + row * 256 + ((kbyte) ^ sw));
                float4 v1 = *(const float4*)(Ab + row * 256 + ((kbyte + 16) ^ sw));
                s8v s;
                s[0]=f2b(v0.x); s[1]=f2b(v0.y); s[2]=f2b(v0.z); s[3]=f2b(v0.w);
                s[4]=f2b(v1.x); s[5]=f2b(v1.y); s[6]=f2b(v1.z); s[7]=f2b(v1.w);
                a[i] = s;
            }
            #pragma unroll
            for (int j = 0; j < 2; ++j) {
                const int row = wn * 32 + j * 16 + (lane & 15);
                const int sw = (row & 7) << 4;
                const int kbyte = kk * 64 + (lane >> 4) * 16;
                bv[j] = *(const s8v*)(Bbuf + row * 128 + (kbyte ^ sw));
            }
            #pragma unroll
            for (int i = 0; i < 2; ++i)
                #pragma unroll
                for (int j = 0; j < 2; ++j)
                    acc[i][j] = MF(a[i], bv[j], acc[i][j]);
        }
        fastbar();                               // reads done before next re-stage
    }
    __syncthreads();
    #pragma unroll
    for (int i = 0; i < 2; ++i)
        #pragma unroll
        for (int j = 0; j < 2; ++j)
            #pragma unroll
            for (int rr = 0; rr < 4; ++rr)
                ts[wm * 32 + i * 16 + (lane >> 4) * 4 + rr][wn * 32 + j * 16 + (lane & 15)] = acc[i][j][rr];
    __syncthreads();
    const int o = tid >> 2, lofs = (tid & 3) * 16;
    float* Sp = St + ((size_t)b * OSo + o) * Ll + l0 + lofs;
    #pragma unroll
    for (int w = 0; w < 4; ++w) {
        float4 v;
        v.x = ts[lofs + w * 4 + 0][o];
        v.y = ts[lofs + w * 4 + 1][o];
        v.z = ts[lofs + w * 4 + 2][o];
        v.w = ts[lofs + w * 4 + 3][o];
        *(float4*)&Sp[w * 4] = v;
    }
}

// ---------------------------------------------------------------------------
// k2: St + a_b, softmax over L, write alpha bf16.  float4-vectorized.
// ---------------------------------------------------------------------------
__global__ __launch_bounds__(256) void k2(const float* __restrict__ St,
                                          const float* __restrict__ a_b,
                                          short* __restrict__ aBf) {
    __shared__ float row[Ll];
    __shared__ float red[8];
    const float* p0 = St + (size_t)blockIdx.x * Ll;
    short* ab = aBf + (size_t)blockIdx.x * Ll;
    const int tid = threadIdx.x;
    const int wave = tid >> 6, lane = tid & 63;
    const float bias = a_b[blockIdx.x & (OSo - 1)];
    const int base = tid * 4;
    float m = -1e30f;
    #pragma unroll
    for (int i = base; i < Ll; i += 1024) {
        float4 a = *(const float4*)&p0[i];
        float4 v;
        v.x = a.x + bias; v.y = a.y + bias;
        v.z = a.z + bias; v.w = a.w + bias;
        *(float4*)&row[i] = v;
        m = fmaxf(m, fmaxf(fmaxf(v.x, v.y), fmaxf(v.z, v.w)));
    }
    #pragma unroll
    for (int off = 32; off; off >>= 1) m = fmaxf(m, __shfl_down(m, off));
    if (lane == 0) red[wave] = m;
    __syncthreads();
    if (tid == 0) red[4] = fmaxf(fmaxf(red[0], red[1]), fmaxf(red[2], red[3]));
    __syncthreads();
    const float M = red[4];
    float s = 0.f;
    #pragma unroll
    for (int i = base; i < Ll; i += 1024) {
        float4 v = *(const float4*)&row[i];
        v.x = __expf(v.x - M); v.y = __expf(v.y - M);
        v.z = __expf(v.z - M); v.w = __expf(v.w - M);
        *(float4*)&row[i] = v;
        s += (v.x + v.y) + (v.z + v.w);
    }
    __syncthreads();
    #pragma unroll
    for (int off = 32; off; off >>= 1) s += __shfl_down(s, off);
    if (lane == 0) red[wave] = s;
    __syncthreads();
    if (tid == 0) red[4] = 1.f / (red[0] + red[1] + red[2] + red[3]);
    __syncthreads();
    const float inv = red[4];
    #pragma unroll
    for (int i = base; i < Ll; i += 1024) {
        float4 v = *(const float4*)&row[i];
        s4v o;
        o[0] = f2b(v.x * inv); o[1] = f2b(v.y * inv);
        o[2] = f2b(v.z * inv); o[3] = f2b(v.w * inv);
        *(s4v*)&ab[i] = o;
    }
}

// ---------------------------------------------------------------------------
// k3: XpP[z] = alpha_half @ X_half, partials stored BF16 (halved traffic).
// tile 64(o)x64(d), split-K=2, dbuf+prefetch+fastbar.  512 blocks.
// ---------------------------------------------------------------------------
struct R3 { s8v al[2]; float4 xv[4]; };

__global__ __launch_bounds__(256) void k3(const float* __restrict__ X,
                                          const short* __restrict__ aBf,
                                          short* __restrict__ XpP) {
    __shared__ __align__(16) char smem[32768];
    float (*ts)[68] = (float(*)[68])smem;                   // epilogue alias
    const int tid = threadIdx.x;
    const int lane = tid & 63, wave = tid >> 6;
    const int wm = wave >> 1, wn = wave & 1;
    const int id = blockIdx.x;
    const int slot = id >> 3;
    const int b = (id & 7) * 2 + (slot >> 5);
    const int inner = slot & 31;
    const int dt = inner & 15, z = inner >> 4;
    const int d0 = dt * 64;
    const float* Xb = X + (size_t)b * Ll * Dd;
    const short* ab = aBf + (size_t)b * OSo * Ll;
    short* outP = XpP + (size_t)z * ((size_t)Bb * OSo * Dd);
    f32x4 acc[2][2] = {};
    const int arow = tid >> 2, akofs = (tid & 3) * 16;
    const int lq = tid & 15, dq = tid >> 4;
    const int lbase = z * 1024;
    R3 cur, nxt;
    #pragma unroll
    for (int w = 0; w < 2; ++w)
        cur.al[w] = *(const s8v*)&ab[(size_t)arow * Ll + lbase + akofs + w * 8];
    #pragma unroll
    for (int i = 0; i < 4; ++i)
        cur.xv[i] = *(const float4*)&Xb[(size_t)(lbase + lq * 4 + i) * Dd + d0 + dq * 4];
    #pragma unroll
    for (int t = 0; t < 16; ++t) {
        short* Aal = (short*)(smem + (t & 1) * 8192);
        short* Xs  = (short*)(smem + 16384 + (t & 1) * 8192);
        #pragma unroll
        for (int w = 0; w < 2; ++w)
            *(s8v*)&Aal[swi(arow, akofs + w * 8)] = cur.al[w];
        {
            const float* f = (const float*)cur.xv;          // f[i*4+j] = X[l=lq*4+i][d=dq*4+j]
            #pragma unroll
            for (int j = 0; j < 4; ++j) {
                const int rowd = dq * 4 + j;
                s4v sj;
                sj[0] = f2b(f[0 * 4 + j]);
                sj[1] = f2b(f[1 * 4 + j]);
                sj[2] = f2b(f[2 * 4 + j]);
                sj[3] = f2b(f[3 * 4 + j]);
                *(s4v*)&Xs[swi(rowd, lq * 4)] = sj;
            }
        }
        fastbar();
        if (t < 15) {
            const int l0 = lbase + (t + 1) * 64;
            #pragma unroll
            for (int w = 0; w < 2; ++w)
                nxt.al[w] = *(const s8v*)&ab[(size_t)arow * Ll + l0 + akofs + w * 8];
            #pragma unroll
            for (int i = 0; i < 4; ++i)
                nxt.xv[i] = *(const float4*)&Xb[(size_t)(l0 + lq * 4 + i) * Dd + d0 + dq * 4];
        }
        #pragma unroll
        for (int kk = 0; kk < 2; ++kk) {
            const int kb = kk * 32 + (lane >> 4) * 8;
            s8v a[2], bb[2];
            #pragma unroll
            for (int i = 0; i < 2; ++i)
                a[i] = *(const s8v*)&Aal[swi(wm * 32 + i * 16 + (lane & 15), kb)];
            #pragma unroll
            for (int j = 0; j < 2; ++j)
                bb[j] = *(const s8v*)&Xs[swi(wn * 32 + j * 16 + (lane & 15), kb)];
            #pragma unroll
            for (int i = 0; i < 2; ++i)
                #pragma unroll
                for (int j = 0; j < 2; ++j)
                    acc[i][j] = MF(a[i], bb[j], acc[i][j]);
        }
        if (t < 15) cur = nxt;
    }
    __syncthreads();
    #pragma unroll
    for (int i = 0; i < 2; ++i)
        #pragma unroll
        for (int j = 0; j < 2; ++j)
            #pragma unroll
            for (int rr = 0; rr < 4; ++rr)
                ts[wm * 32 + i * 16 + (lane >> 4) * 4 + rr][wn * 32 + j * 16 + (lane & 15)] = acc[i][j][rr];
    __syncthreads();
    const int o = tid >> 2, dofs = (tid & 3) * 16;
    short* op = outP + ((size_t)b * OSo + o) * Dd + d0 + dofs;
    #pragma unroll
    for (int w = 0; w < 2; ++w) {
        float4 v0 = *(const float4*)&ts[o][dofs + w * 8];
        float4 v1 = *(const float4*)&ts[o][dofs + w * 8 + 4];
        s8v s;
        s[0]=f2b(v0.x); s[1]=f2b(v0.y); s[2]=f2b(v0.z); s[3]=f2b(v0.w);
        s[4]=f2b(v1.x); s[5]=f2b(v1.y); s[6]=f2b(v1.z); s[7]=f2b(v1.w);
        *(s8v*)&op[w * 8] = s;
    }
}

// ---------------------------------------------------------------------------
// k4: Xh = bf16(relu(BN((XpP0+XpP1)@h_w + h_b)))  tile 64x64, dbuf+prefetch.
// BF16 partials summed in f32 at staging.  XCD-grouped by m-tile.
// ---------------------------------------------------------------------------
struct R4 { s8v p[4]; s8v w[2]; };

__global__ __launch_bounds__(256) void k4(const short* __restrict__ XpP,
                                          const short* __restrict__ h_wT,
                                          const float* __restrict__ h_b,
                                          const float* __restrict__ gamma,
                                          const float* __restrict__ beta,
                                          const float* __restrict__ mean,
                                          const float* __restrict__ var,
                                          short* __restrict__ Xh) {
    __shared__ __align__(16) char smem[32768];
    short* tsb = (short*)smem;                              // epilogue alias [64][64]
    const int tid = threadIdx.x, lane = tid & 63, wave = tid >> 6;
    const int wm = wave >> 1, wn = wave & 1;
    const int id = blockIdx.x;
    const int slot = id >> 3;
    const int mt = (id & 7) * 2 + (slot >> 4);              // same mt -> same XCD
    const int ht = slot & 15;
    const int h0 = ht * 64, m0 = mt * 64;
    const int r = tid >> 2, kofs = (tid & 3) * 16;
    const size_t ZS = (size_t)Bb * OSo * Dd;
    f32x4 acc[2][2] = {};
    R4 cur, nxt;
    #pragma unroll
    for (int w = 0; w < 2; ++w) {
        const short* p0 = XpP + (size_t)(m0 + r) * Dd + kofs + w * 8;
        cur.p[w*2]   = *(const s8v*)&p0[0];
        cur.p[w*2+1] = *(const s8v*)&p0[ZS];
        cur.w[w]     = *(const s8v*)&h_wT[(size_t)(h0 + r) * Dd + kofs + w * 8];
    }
    #pragma unroll
    for (int t = 0; t < 16; ++t) {
        short* As = (short*)(smem + (t & 1) * 8192);
        short* Bs = (short*)(smem + 16384 + (t & 1) * 8192);
        #pragma unroll
        for (int w = 0; w < 2; ++w) {
            s8v q0 = cur.p[w*2], q1 = cur.p[w*2+1];
            s8v s;
            #pragma unroll
            for (int e = 0; e < 8; ++e) s[e] = f2b(b2f(q0[e]) + b2f(q1[e]));
            *(s8v*)&As[swi(r, kofs + w * 8)] = s;
            *(s8v*)&Bs[swi(r, kofs + w * 8)] = cur.w[w];
        }
        fastbar();
        if (t < 15) {
            const int k0 = (t + 1) * 64;
            #pragma unroll
            for (int w = 0; w < 2; ++w) {
                const short* p0 = XpP + (size_t)(m0 + r) * Dd + k0 + kofs + w * 8;
                nxt.p[w*2]   = *(const s8v*)&p0[0];
                nxt.p[w*2+1] = *(const s8v*)&p0[ZS];
                nxt.w[w]     = *(const s8v*)&h_wT[(size_t)(h0 + r) * Dd + k0 + kofs + w * 8];
            }
        }
        #pragma unroll
        for (int kk = 0; kk < 2; ++kk) {
            const int kb = kk * 32 + (lane >> 4) * 8;
            s8v a[2], bb[2];
            #pragma unroll
            for (int i = 0; i < 2; ++i)
                a[i] = *(const s8v*)&As[swi(wm * 32 + i * 16 + (lane & 15), kb)];
            #pragma unroll
            for (int j = 0; j < 2; ++j)
                bb[j] = *(const s8v*)&Bs[swi(wn * 32 + j * 16 + (lane & 15), kb)];
            #pragma unroll
            for (int i = 0; i < 2; ++i)
                #pragma unroll
                for (int j = 0; j < 2; ++j)
                    acc[i][j] = MF(a[i], bb[j], acc[i][j]);
        }
        if (t < 15) cur = nxt;
    }
    __syncthreads();
    #pragma unroll
    for (int j = 0; j < 2; ++j) {
        const int h = h0 + wn * 32 + j * 16 + (lane & 15);
        const float sc = gamma[h] * rsqrtf(var[h] + BN_EPS);
        const float of = (h_b[h] - mean[h]) * sc + beta[h];
        #pragma unroll
        for (int i = 0; i < 2; ++i)
            #pragma unroll
            for (int rr = 0; rr < 4; ++rr) {
                const int ml = wm * 32 + i * 16 + (lane >> 4) * 4 + rr;
                tsb[ml * 64 + wn * 32 + j * 16 + (lane & 15)] = f2b(fmaxf(0.f, acc[i][j][rr] * sc + of));
            }
    }
    __syncthreads();
    #pragma unroll
    for (int w = 0; w < 2; ++w)
        *(s8v*)&Xh[(size_t)(m0 + r) * LABh + h0 + kofs + w * 8] = *(const s8v*)&tsb[r * 64 + kofs + w * 8];
}

// ---------------------------------------------------------------------------
// k56: fused scores+softmax+weighted-sum.  (round-12 exact)
// ---------------------------------------------------------------------------
struct R56 { float4 ld; s8v xh[2]; };

__global__ __launch_bounds__(256) void k56(const int* __restrict__ cand,
                                           const float* __restrict__ labD,
                                           const short* __restrict__ Xh,
                                           float* __restrict__ out) {
    __shared__ __align__(16) char smem[20608];
    float (*ts)[68] = (float(*)[68])smem;                   // alias after loop
    float (*al)[64] = (float(*)[64])(smem + 4608);
    int* cidx = (int*)(smem + 20480);
    const int tid = threadIdx.x, lane = tid & 63, wave = tid >> 6;
    const int id = blockIdx.x;
    const int slot = id >> 3;
    const int b = (id & 7) * 2 + (slot >> 4);               // XCD-grouped by b
    const int c0 = (slot & 15) * 16;
    if (tid < 16) cidx[tid] = cand[b * NCc + c0 + tid];
    __syncthreads();
    const int ar = tid >> 4, ak = (tid & 15) * 4;
    const int br = tid >> 2, bk = (tid & 3) * 16;
    const float* lrow = labD + (size_t)cidx[ar] * LABh;
    const short* xb = Xh + (size_t)b * OSo * LABh;
    f32x4 acc = {};
    R56 cur, nxt;
    cur.ld    = *(const float4*)&lrow[ak];
    cur.xh[0] = *(const s8v*)&xb[(size_t)br * LABh + bk];
    cur.xh[1] = *(const s8v*)&xb[(size_t)br * LABh + bk + 8];
    #pragma unroll
    for (int t = 0; t < 16; ++t) {
        short* As = (short*)(smem + (t & 1) * 10240);
        short* Bs = As + 1024;
        {
            s4v sa;
            sa[0] = f2b(cur.ld.x); sa[1] = f2b(cur.ld.y);
            sa[2] = f2b(cur.ld.z); sa[3] = f2b(cur.ld.w);
            *(s4v*)&As[swi(ar, ak)] = sa;
            *(s8v*)&Bs[swi(br, bk)]     = cur.xh[0];
            *(s8v*)&Bs[swi(br, bk + 8)] = cur.xh[1];
        }
        fastbar();
        if (t < 15) {
            const int k0 = (t + 1) * 64;
            nxt.ld    = *(const float4*)&lrow[k0 + ak];
            nxt.xh[0] = *(const s8v*)&xb[(size_t)br * LABh + k0 + bk];
            nxt.xh[1] = *(const s8v*)&xb[(size_t)br * LABh + k0 + bk + 8];
        }
        #pragma unroll
        for (int kk = 0; kk < 2; ++kk) {
            const int kb = kk * 32 + (lane >> 4) * 8;
            s8v a  = *(const s8v*)&As[swi(lane & 15, kb)];
            s8v bv = *(const s8v*)&Bs[swi(wave * 16 + (lane & 15), kb)];
            acc = MF(a, bv, acc);
        }
        if (t < 15) cur = nxt;
    }
    __syncthreads();
    #pragma unroll
    for (int rr = 0; rr < 4; ++rr)
        ts[(lane >> 4) * 4 + rr][wave * 16 + (lane & 15)] = acc[rr];
    __syncthreads();
    {
        const int cl = tid >> 4, t16 = tid & 15;
        float v[4];
        float m = -1e30f;
        #pragma unroll
        for (int j = 0; j < 4; ++j) { v[j] = ts[cl][t16 + j * 16]; m = fmaxf(m, v[j]); }
        #pragma unroll
        for (int off = 8; off; off >>= 1) m = fmaxf(m, __shfl_xor(m, off, 16));
        float s = 0.f;
        #pragma unroll
        for (int j = 0; j < 4; ++j) { v[j] = __expf(v[j] - m); s += v[j]; }
        #pragma unroll
        for (int off = 8; off; off >>= 1) s += __shfl_xor(s, off, 16);
        const float inv = 1.f / s;
        #pragma unroll
        for (int j = 0; j < 4; ++j) al[cl][t16 + j * 16] = v[j] * inv;
    }
    __syncthreads();
    const int h0 = tid * 4;
    float acc2[16][4] = {};
    for (int o = 0; o < OSo; ++o) {
        s4v xv = *(const s4v*)&xb[(size_t)o * LABh + h0];
        const float x0 = b2f(xv[0]), x1 = b2f(xv[1]), x2 = b2f(xv[2]), x3 = b2f(xv[3]);
        #pragma unroll
        for (int c = 0; c < 16; ++c) {
            const float w = al[c][o];
            acc2[c][0] += w * x0; acc2[c][1] += w * x1;
            acc2[c][2] += w * x2; acc2[c][3] += w * x3;
        }
    }
    #pragma unroll
    for (int c = 0; c < 16; ++c) {
        float4 v; v.x = acc2[c][0]; v.y = acc2[c][1]; v.z = acc2[c][2]; v.w = acc2[c][3];
        *(float4*)&out[((size_t)b * NCc + c0 + c) * LABh + h0] = v;
    }
}

// ---------------------------------------------------------------------------
extern "C" void kernel_launch(void* const* d_in, const int* in_sizes, int n_in,
                              void* d_out, int out_size, void* d_ws, size_t ws_size,
                              hipStream_t stream) {
    (void)in_sizes; (void)n_in; (void)out_size; (void)ws_size;
    const float* X      = (const float*)d_in[0];
    const int*   cand   = (const int*)  d_in[1];
    const float* a_w    = (const float*)d_in[2];
    const float* a_b    = (const float*)d_in[3];
    const float* h_w    = (const float*)d_in[4];
    const float* h_b    = (const float*)d_in[5];
    const float* gamma  = (const float*)d_in[6];
    const float* beta   = (const float*)d_in[7];
    const float* mean   = (const float*)d_in[8];
    const float* var    = (const float*)d_in[9];
    const float* labDesc= (const float*)d_in[10];
    float* outp = (float*)d_out;

    char* ws = (char*)d_ws;
    float* St   = (float*)ws;                               // 8MB; XpP aliases after k2
    short* XpP  = (short*)ws;                               // 4MB (2 bf16 partials)
    short* aBf  = (short*)(ws + ((size_t)16 << 20));        // 4MB alpha bf16
    short* Xh   = (short*)(ws + ((size_t)20 << 20));        // 2MB
    short* a_wT = (short*)(ws + ((size_t)26 << 20));        // 128KB
    short* h_wT = (short*)(ws + ((size_t)27 << 20));        // 2MB

    k0 <<<272,          256, 0, stream>>>(h_w, a_w, h_wT, a_wT);
    k1 <<<dim3(32, 16), 256, 0, stream>>>(X, a_wT, St);
    k2 <<<Bb * OSo,     256, 0, stream>>>(St, a_b, aBf);
    k3 <<<512,          256, 0, stream>>>(X, aBf, XpP);
    k4 <<<256,          256, 0, stream>>>(XpP, h_wT, h_b, gamma, beta, mean, var, Xh);
    k56<<<256,          256, 0, stream>>>(cand, labDesc, Xh, outp);
}